// Round 9
// baseline (646.528 us; speedup 1.0000x reference)
//
#include <hip/hip_runtime.h>

#define LRELU(x) fmaxf((x), 0.2f*(x))   // identical result to x>0?x:0.2x
#define ZPAD(f) ((f) + 4*((f)>>6))      // 640-float row -> 680 padded (4/head)

static inline int cdiv(int a, int b) { return (a + b - 1) / b; }

// ---------------------------------------------------------------------------
// prep (merged branches): wal[h*64+k] = sum_d W[k, h*DH+d] * al[h*DH+d].
// ---------------------------------------------------------------------------
template<int H, int DH>
__global__ void prep_wal2_kernel(const float* __restrict__ WA, const float* __restrict__ alA,
                                 const float* __restrict__ arA, float* __restrict__ walA,
                                 float* __restrict__ warA, int nbA,
                                 const float* __restrict__ WB, const float* __restrict__ alB,
                                 const float* __restrict__ arB, float* __restrict__ walB,
                                 float* __restrict__ warB) {
  constexpr int K = 64;
  constexpr int HD = H * DH;
  const float *W, *al, *ar; float *wal, *war; int bid;
  if (blockIdx.x < (unsigned)nbA) { W=WA; al=alA; ar=arA; wal=walA; war=warA; bid=blockIdx.x; }
  else { W=WB; al=alB; ar=arB; wal=walB; war=warB; bid=blockIdx.x-nbA; }
  const int wv = threadIdx.x >> 6, lane = threadIdx.x & 63;
  const int o = bid * (blockDim.x >> 6) + wv;
  if (o >= H * K) return;
  const int h = o / K, k = o - h * K;
  float pl = 0.f, pr = 0.f;
#pragma unroll
  for (int j = 0; j < DH / 64; j++) {
    int d = j * 64 + lane;
    float w = W[(size_t)k * HD + h * DH + d];
    pl += w * al[h * DH + d];
    pr += w * ar[h * DH + d];
  }
#pragma unroll
  for (int off = 32; off >= 1; off >>= 1) {
    pl += __shfl_xor(pl, off);
    pr += __shfl_xor(pr, off);
  }
  if (lane == 0) { wal[o] = pl; war[o] = pr; }
}

// ---------------------------------------------------------------------------
// el/er for layer 1 (merged). One wave per node.
// ---------------------------------------------------------------------------
__global__ void elr10_2_kernel(const float* __restrict__ xA, const float* __restrict__ walA,
                               const float* __restrict__ warA, float* __restrict__ elA,
                               float* __restrict__ erA, int NA, int nbA,
                               const float* __restrict__ xB, const float* __restrict__ walB,
                               const float* __restrict__ warB, float* __restrict__ elB,
                               float* __restrict__ erB, int NB) {
  const float *x, *wal, *war; float *el, *er; int N, bid;
  if (blockIdx.x < (unsigned)nbA) { x=xA; wal=walA; war=warA; el=elA; er=erA; N=NA; bid=blockIdx.x; }
  else { x=xB; wal=walB; war=warB; el=elB; er=erB; N=NB; bid=blockIdx.x-nbA; }
  const int wv = threadIdx.x >> 6, lane = threadIdx.x & 63;
  const int n = bid * (blockDim.x >> 6) + wv;
  if (n >= N) return;
  const float xv = x[(size_t)n * 64 + lane];
#pragma unroll
  for (int h = 0; h < 10; h++) {
    float pl = xv * wal[h * 64 + lane];
    float pr = xv * war[h * 64 + lane];
#pragma unroll
    for (int off = 32; off >= 1; off >>= 1) {
      pl += __shfl_xor(pl, off);
      pr += __shfl_xor(pr, off);
    }
    if (lane == 0) { el[(size_t)n * 10 + h] = pl; er[(size_t)n * 10 + h] = pr; }
  }
}

// ---------------------------------------------------------------------------
// CSR build (merged): deg count -> wave-atomic row offsets -> scatter
// ---------------------------------------------------------------------------
__global__ void deg2_kernel(const int* __restrict__ dstA, int* __restrict__ degA, int EA, int nbA,
                            const int* __restrict__ dstB, int* __restrict__ degB, int EB) {
  const int* dst; int* deg; int E, t;
  if (blockIdx.x < (unsigned)nbA) { dst=dstA; deg=degA; E=EA; t=blockIdx.x*256+threadIdx.x; }
  else { dst=dstB; deg=degB; E=EB; t=(blockIdx.x-nbA)*256+threadIdx.x; }
  if (t < E) atomicAdd(&deg[dst[t]], 1);
}

__global__ void rowptr2_kernel(const int* __restrict__ degA, int* __restrict__ rpA,
                               int* __restrict__ curA, int* __restrict__ cntA, int NA, int nbA,
                               const int* __restrict__ degB, int* __restrict__ rpB,
                               int* __restrict__ curB, int* __restrict__ cntB, int NB) {
  const int* deg; int *rp, *cur, *cnt; int N, t;
  if (blockIdx.x < (unsigned)nbA) { deg=degA; rp=rpA; cur=curA; cnt=cntA; N=NA; t=blockIdx.x*256+threadIdx.x; }
  else { deg=degB; rp=rpB; cur=curB; cnt=cntB; N=NB; t=(blockIdx.x-nbA)*256+threadIdx.x; }
  int lane = threadIdx.x & 63;
  int v = (t < N) ? deg[t] : 0;
  int x = v;
#pragma unroll
  for (int off = 1; off < 64; off <<= 1) {
    int y = __shfl_up(x, off);
    if (lane >= off) x += y;
  }
  int total = __shfl(x, 63);
  int base = 0;
  if (lane == 0 && total > 0) base = atomicAdd(cnt, total);
  base = __shfl(base, 0);
  int excl = base + x - v;
  if (t < N) { rp[t] = excl; cur[t] = excl; }
}

__global__ void scatter2_kernel(const int* __restrict__ srcA, const int* __restrict__ dstA,
                                int* __restrict__ curA, int* __restrict__ outA, int EA, int nbA,
                                const int* __restrict__ srcB, const int* __restrict__ dstB,
                                int* __restrict__ curB, int* __restrict__ outB, int EB) {
  const int *src, *dst; int *cur, *out; int E, t;
  if (blockIdx.x < (unsigned)nbA) { src=srcA; dst=dstA; cur=curA; out=outA; E=EA; t=blockIdx.x*256+threadIdx.x; }
  else { src=srcB; dst=dstB; cur=curB; out=outB; E=EB; t=(blockIdx.x-nbA)*256+threadIdx.x; }
  if (t >= E) return;
  int slot = atomicAdd(&cur[dst[t]], 1);
  out[slot] = src[t];
}

// ---------------------------------------------------------------------------
// Layer-1 aggregation (merged): one wave per node, all 10 heads in registers.
// ---------------------------------------------------------------------------
__global__ void aggr_z10_2_kernel(const int* __restrict__ rpA, const int* __restrict__ degA,
                                  const int* __restrict__ srcsA, const float* __restrict__ xA,
                                  const float* __restrict__ elA, const float* __restrict__ erA,
                                  float* __restrict__ zA, int NA, int nbA,
                                  const int* __restrict__ rpB, const int* __restrict__ degB,
                                  const int* __restrict__ srcsB, const float* __restrict__ xB,
                                  const float* __restrict__ elB, const float* __restrict__ erB,
                                  float* __restrict__ zB, int NB) {
  const int *rp, *degp, *srcs; const float *x, *el, *er; float *z; int N, bid;
  if (blockIdx.x < (unsigned)nbA) { rp=rpA; degp=degA; srcs=srcsA; x=xA; el=elA; er=erA; z=zA; N=NA; bid=blockIdx.x; }
  else { rp=rpB; degp=degB; srcs=srcsB; x=xB; el=elB; er=erB; z=zB; N=NB; bid=blockIdx.x-nbA; }
  const int wv = threadIdx.x >> 6, lane = threadIdx.x & 63;
  const int n = bid * (blockDim.x >> 6) + wv;
  if (n >= N) return;
  const int beg = rp[n], dg = degp[n];
  const float2* elv = (const float2*)el;
  const float2* erv = (const float2*)er;
  float ern[10];
#pragma unroll
  for (int j = 0; j < 5; j++) {
    float2 t2 = erv[(size_t)n * 5 + j];
    ern[2 * j] = t2.x; ern[2 * j + 1] = t2.y;
  }
  float den[10], acc[10];
#pragma unroll
  for (int h = 0; h < 10; h++) { den[h] = 0.f; acc[h] = 0.f; }
  int i = 0;
  for (; i + 1 < dg; i += 2) {
    int s0 = srcs[beg + i], s1 = srcs[beg + i + 1];
    float xv0 = x[(size_t)s0 * 64 + lane];
    float xv1 = x[(size_t)s1 * 64 + lane];
    float w0[10], w1[10];
#pragma unroll
    for (int j = 0; j < 5; j++) {
      float2 a = elv[(size_t)s0 * 5 + j];
      float2 c = elv[(size_t)s1 * 5 + j];
      w0[2 * j] = a.x; w0[2 * j + 1] = a.y;
      w1[2 * j] = c.x; w1[2 * j + 1] = c.y;
    }
#pragma unroll
    for (int h = 0; h < 10; h++) {
      float ea = __expf(LRELU(w0[h] + ern[h]));
      float eb = __expf(LRELU(w1[h] + ern[h]));
      den[h] += ea + eb;
      acc[h] += ea * xv0 + eb * xv1;
    }
  }
  if (i < dg) {
    int s0 = srcs[beg + i];
    float xv0 = x[(size_t)s0 * 64 + lane];
    float w0[10];
#pragma unroll
    for (int j = 0; j < 5; j++) {
      float2 a = elv[(size_t)s0 * 5 + j];
      w0[2 * j] = a.x; w0[2 * j + 1] = a.y;
    }
#pragma unroll
    for (int h = 0; h < 10; h++) {
      float ea = __expf(LRELU(w0[h] + ern[h]));
      den[h] += ea;
      acc[h] += ea * xv0;
    }
  }
#pragma unroll
  for (int h = 0; h < 10; h++)
    z[(size_t)n * 640 + h * 64 + lane] = (dg > 0) ? acc[h] / den[h] : 0.f;
}

// ---------------------------------------------------------------------------
// Layer-2 aggregation (merged, H=1): one wave per node over h1sum (64-dim).
// ---------------------------------------------------------------------------
__global__ void aggr_z1_2_kernel(const int* __restrict__ rpA, const int* __restrict__ degA,
                                 const int* __restrict__ srcsA, const float* __restrict__ hA,
                                 const float* __restrict__ elA, const float* __restrict__ erA,
                                 float* __restrict__ zA, int NA, int nbA,
                                 const int* __restrict__ rpB, const int* __restrict__ degB,
                                 const int* __restrict__ srcsB, const float* __restrict__ hB,
                                 const float* __restrict__ elB, const float* __restrict__ erB,
                                 float* __restrict__ zB, int NB) {
  const int *rp, *degp, *srcs; const float *hin, *el, *er; float *z; int N, bid;
  if (blockIdx.x < (unsigned)nbA) { rp=rpA; degp=degA; srcs=srcsA; hin=hA; el=elA; er=erA; z=zA; N=NA; bid=blockIdx.x; }
  else { rp=rpB; degp=degB; srcs=srcsB; hin=hB; el=elB; er=erB; z=zB; N=NB; bid=blockIdx.x-nbA; }
  const int wv = threadIdx.x >> 6, lane = threadIdx.x & 63;
  const int n = bid * (blockDim.x >> 6) + wv;
  if (n >= N) return;
  const int beg = rp[n], dg = degp[n];
  const float ern = er[n];
  float den = 0.f, acc = 0.f;
  int i = 0;
  for (; i + 1 < dg; i += 2) {
    int s0 = srcs[beg + i], s1 = srcs[beg + i + 1];
    float x0 = __expf(LRELU(el[s0] + ern));
    float x1 = __expf(LRELU(el[s1] + ern));
    den += x0 + x1;
    acc += x0 * hin[(size_t)s0 * 64 + lane] + x1 * hin[(size_t)s1 * 64 + lane];
  }
  if (i < dg) {
    int s0 = srcs[beg + i];
    float x0 = __expf(LRELU(el[s0] + ern));
    den += x0;
    acc += x0 * hin[(size_t)s0 * 64 + lane];
  }
  z[(size_t)n * 64 + lane] = (dg > 0) ? acc / den : 0.f;
}

// ---------------------------------------------------------------------------
// Layer-1 GEMM (register-tiled) + relu + head-sum + fused el2/er2.
// 640 thr, 16 nodes/block. Thread = 4 nodes x 4 consecutive outputs (float4 W).
// LDS rows padded 640->680 (+4/head) so the 4 heads/wave hit distinct banks.
// ---------------------------------------------------------------------------
__global__ void gemm_sumheads2_kernel(
    const float* __restrict__ zA, const float* __restrict__ WA, const float* __restrict__ bA,
    const float* __restrict__ wal2A, const float* __restrict__ war2A, float* __restrict__ h1A,
    float* __restrict__ el2A, float* __restrict__ er2A, int NA, int nbA,
    const float* __restrict__ zB, const float* __restrict__ WB, const float* __restrict__ bB,
    const float* __restrict__ wal2B, const float* __restrict__ war2B, float* __restrict__ h1B,
    float* __restrict__ el2B, float* __restrict__ er2B, int NB) {
  constexpr int NPB = 16;
  __shared__ float zs[NPB][680];
  const float *z, *W, *bb, *wal2, *war2; float *h1sum, *el2, *er2; int N, tile;
  if (blockIdx.x < (unsigned)nbA) { z=zA; W=WA; bb=bA; wal2=wal2A; war2=war2A; h1sum=h1A; el2=el2A; er2=er2A; N=NA; tile=blockIdx.x; }
  else { z=zB; W=WB; bb=bB; wal2=wal2B; war2=war2B; h1sum=h1B; el2=el2B; er2=er2B; N=NB; tile=blockIdx.x-nbA; }
  const int f = threadIdx.x;      // 640
  const int n0 = tile * NPB;
  const int pf = ZPAD(f);
#pragma unroll
  for (int i = 0; i < NPB; i++) {
    int n = n0 + i;
    zs[i][pf] = (n < N) ? z[(size_t)n * 640 + f] : 0.f;
  }
  __syncthreads();
  const int f4 = f % 160;         // outputs 4*f4 .. 4*f4+3
  const int ng = f / 160;         // node group: nodes ng*4 .. ng*4+3
  const int head = f4 >> 4;
  const int base = 68 * head;     // padded offset of k=0 within this head
  float acc[4][4];
#pragma unroll
  for (int i = 0; i < 4; i++)
#pragma unroll
    for (int j = 0; j < 4; j++) acc[i][j] = 0.f;
  const float4* W4 = (const float4*)W;
#pragma unroll 4
  for (int k4 = 0; k4 < 16; k4++) {
    float4 zq[4];
#pragma unroll
    for (int i = 0; i < 4; i++)
      zq[i] = *(const float4*)&zs[ng * 4 + i][base + 4 * k4];
#pragma unroll
    for (int j4 = 0; j4 < 4; j4++) {
      const int k = 4 * k4 + j4;
      const float4 w4 = W4[(size_t)k * 160 + f4];
#pragma unroll
      for (int i = 0; i < 4; i++) {
        const float zv = j4 == 0 ? zq[i].x : j4 == 1 ? zq[i].y : j4 == 2 ? zq[i].z : zq[i].w;
        acc[i][0] = fmaf(zv, w4.x, acc[i][0]);
        acc[i][1] = fmaf(zv, w4.y, acc[i][1]);
        acc[i][2] = fmaf(zv, w4.z, acc[i][2]);
        acc[i][3] = fmaf(zv, w4.w, acc[i][3]);
      }
    }
  }
  const float4 b4 = ((const float4*)bb)[f4];
  __syncthreads();
#pragma unroll
  for (int i = 0; i < 4; i++) {
    float* row = &zs[ng * 4 + i][ZPAD(4 * f4)];   // 4 consecutive (same head)
    row[0] = fmaxf(acc[i][0] + b4.x, 0.f);
    row[1] = fmaxf(acc[i][1] + b4.y, 0.f);
    row[2] = fmaxf(acc[i][2] + b4.z, 0.f);
    row[3] = fmaxf(acc[i][3] + b4.w, 0.f);
  }
  __syncthreads();
  const int lane = threadIdx.x & 63;
  for (int idx = threadIdx.x; idx < NPB * 64; idx += 640) {
    const int i = idx >> 6, d = idx & 63;
    float s = 0.f;
#pragma unroll
    for (int h = 0; h < 10; h++) s += zs[i][68 * h + d];
    const int n = n0 + i;
    float pl = s * wal2[d], pr = s * war2[d];
#pragma unroll
    for (int off = 32; off >= 1; off >>= 1) {
      pl += __shfl_xor(pl, off);
      pr += __shfl_xor(pr, off);
    }
    if (n < N) {
      h1sum[(size_t)n * 64 + d] = s;
      if (lane == 0) { el2[n] = pl; er2[n] = pr; }
    }
  }
}

// ---------------------------------------------------------------------------
// Layer-2 GEMM (register-tiled) + relu + fused segment-max readout.
// 128 thr, 8 nodes/block. Thread = 2 nodes x 4 consecutive outputs.
// ---------------------------------------------------------------------------
__global__ void gemm2_readout2_kernel(
    const float* __restrict__ zA, const float* __restrict__ WA, const float* __restrict__ bA,
    const int* __restrict__ gidA, int NA, int coA, int nbA,
    const float* __restrict__ zB, const float* __restrict__ WB, const float* __restrict__ bB,
    const int* __restrict__ gidB, int NB, int coB,
    float* __restrict__ readout) {
  constexpr int NPB = 8;
  __shared__ float zs[NPB][64];
  const float *z, *W, *bb; const int* gid; int N, colOff, tile;
  if (blockIdx.x < (unsigned)nbA) { z=zA; W=WA; bb=bA; gid=gidA; N=NA; colOff=coA; tile=blockIdx.x; }
  else { z=zB; W=WB; bb=bB; gid=gidB; N=NB; colOff=coB; tile=blockIdx.x-nbA; }
  const int f = threadIdx.x;      // 128
  const int n0 = tile * NPB;
  for (int idx = f; idx < NPB * 64; idx += 128) {
    int i = idx >> 6, k = idx & 63;
    int n = n0 + i;
    zs[i][k] = (n < N) ? z[(size_t)n * 64 + k] : 0.f;
  }
  __syncthreads();
  const int f4 = f % 32;          // outputs 4*f4 .. 4*f4+3
  const int ng = f / 32;          // node group: nodes ng*2, ng*2+1
  float acc[2][4];
#pragma unroll
  for (int i = 0; i < 2; i++)
#pragma unroll
    for (int j = 0; j < 4; j++) acc[i][j] = 0.f;
  const float4* W4 = (const float4*)W;
#pragma unroll 4
  for (int k4 = 0; k4 < 16; k4++) {
    float4 zq[2];
#pragma unroll
    for (int i = 0; i < 2; i++)
      zq[i] = *(const float4*)&zs[ng * 2 + i][4 * k4];
#pragma unroll
    for (int j4 = 0; j4 < 4; j4++) {
      const int k = 4 * k4 + j4;
      const float4 w4 = W4[(size_t)k * 32 + f4];
#pragma unroll
      for (int i = 0; i < 2; i++) {
        const float zv = j4 == 0 ? zq[i].x : j4 == 1 ? zq[i].y : j4 == 2 ? zq[i].z : zq[i].w;
        acc[i][0] = fmaf(zv, w4.x, acc[i][0]);
        acc[i][1] = fmaf(zv, w4.y, acc[i][1]);
        acc[i][2] = fmaf(zv, w4.z, acc[i][2]);
        acc[i][3] = fmaf(zv, w4.w, acc[i][3]);
      }
    }
  }
  const float4 b4 = ((const float4*)bb)[f4];
#pragma unroll
  for (int i = 0; i < 2; i++) {
    const int n = n0 + ng * 2 + i;
    if (n < N) {
      const int g = gid[n];
      unsigned int* ro = (unsigned int*)&readout[g * 256 + colOff + 4 * f4];
      atomicMax(ro + 0, __float_as_uint(fmaxf(acc[i][0] + b4.x, 0.f)));
      atomicMax(ro + 1, __float_as_uint(fmaxf(acc[i][1] + b4.y, 0.f)));
      atomicMax(ro + 2, __float_as_uint(fmaxf(acc[i][2] + b4.z, 0.f)));
      atomicMax(ro + 3, __float_as_uint(fmaxf(acc[i][3] + b4.w, 0.f)));
    }
  }
}

// MLP: relu(concat @ W1 + b1) @ W2 + b2 -> relu -> out[32]
__global__ void mlp_kernel(const float* __restrict__ readout, const float* __restrict__ W1,
                           const float* __restrict__ b1, const float* __restrict__ W2,
                           const float* __restrict__ b2, float* __restrict__ out) {
  int b = blockIdx.x;   // 32
  int j = threadIdx.x;  // 128
  __shared__ float rs[256];
  rs[j] = readout[b * 256 + j];
  rs[j + 128] = readout[b * 256 + 128 + j];
  __syncthreads();
  float acc = b1[j];
#pragma unroll 8
  for (int k = 0; k < 256; k++) acc += rs[k] * W1[k * 128 + j];
  acc = fmaxf(acc, 0.f);
  float p = acc * W2[j];
#pragma unroll
  for (int off = 32; off >= 1; off >>= 1) p += __shfl_xor(p, off);
  __shared__ float wsum[2];
  if ((threadIdx.x & 63) == 0) wsum[threadIdx.x >> 6] = p;
  __syncthreads();
  if (threadIdx.x == 0) {
    float s = wsum[0] + wsum[1] + b2[0];
    out[b] = fmaxf(s, 0.f);
  }
}

// ---------------------------------------------------------------------------
extern "C" void kernel_launch(void* const* d_in, const int* in_sizes, int n_in,
                              void* d_out, int out_size, void* d_ws, size_t ws_size,
                              hipStream_t stream) {
  const float* x_lig = (const float*)d_in[0];
  const int* src_lig = (const int*)d_in[1];
  const int* dst_lig = (const int*)d_in[2];
  const int* gid_lig = (const int*)d_in[3];
  const float* x_rec = (const float*)d_in[4];
  const int* src_rec = (const int*)d_in[5];
  const int* dst_rec = (const int*)d_in[6];
  const int* gid_rec = (const int*)d_in[7];
  const float* W1l = (const float*)d_in[8];
  const float* al1l = (const float*)d_in[9];
  const float* ar1l = (const float*)d_in[10];
  const float* b1l = (const float*)d_in[11];
  const float* W2l = (const float*)d_in[12];
  const float* al2l = (const float*)d_in[13];
  const float* ar2l = (const float*)d_in[14];
  const float* b2l = (const float*)d_in[15];
  const float* W1r = (const float*)d_in[16];
  const float* al1r = (const float*)d_in[17];
  const float* ar1r = (const float*)d_in[18];
  const float* b1r = (const float*)d_in[19];
  const float* W2r = (const float*)d_in[20];
  const float* al2r = (const float*)d_in[21];
  const float* ar2r = (const float*)d_in[22];
  const float* b2r = (const float*)d_in[23];
  const float* W_lin1 = (const float*)d_in[24];
  const float* b_lin1 = (const float*)d_in[25];
  const float* W_lin2 = (const float*)d_in[26];
  const float* b_lin2 = (const float*)d_in[27];

  const int NL = 10000, EL = 80000, NR = 30000, ER = 480000;
  float* p = (float*)d_ws;
  // per-branch buffers (branches now run concurrently in merged dispatches)
  float* zL = p;      p += (size_t)NL * 640;
  float* zR = p;      p += (size_t)NR * 640;
  float* z2L = p;     p += (size_t)NL * 64;
  float* z2R = p;     p += (size_t)NR * 64;
  float* h1L = p;     p += (size_t)NL * 64;
  float* h1R = p;     p += (size_t)NR * 64;
  float* el1L = p;    p += (size_t)NL * 10;
  float* er1L = p;    p += (size_t)NL * 10;
  float* el1R = p;    p += (size_t)NR * 10;
  float* er1R = p;    p += (size_t)NR * 10;
  float* el2L = p;    p += NL;
  float* er2L = p;    p += NL;
  float* el2R = p;    p += NR;
  float* er2R = p;    p += NR;
  float* wal1l = p;   p += 640;
  float* war1l = p;   p += 640;
  float* wal1r = p;   p += 640;
  float* war1r = p;   p += 640;
  float* wal2l = p;   p += 64;
  float* war2l = p;   p += 64;
  float* wal2r = p;   p += 64;
  float* war2r = p;   p += 64;
  // zero region: readout + deg + counters
  float* zero_base = p;
  float* readout = p; p += 32 * 256;
  int* ip = (int*)p;
  int* degL = ip;     ip += NL;
  int* cntL = ip;     ip += 1;
  int* degR = ip;     ip += NR;
  int* cntR = ip;     ip += 1;
  size_t zero_bytes = (size_t)((char*)ip - (char*)zero_base);
  // non-zeroed CSR scratch
  int* rpL = ip;      ip += NL;
  int* curL = ip;     ip += NL;
  int* srcsL = ip;    ip += EL;
  int* rpR = ip;      ip += NR;
  int* curR = ip;     ip += NR;
  int* srcsR = ip;    ip += ER;

  hipMemsetAsync(zero_base, 0, zero_bytes, stream);

  // prep (merged lig+rec)
  prep_wal2_kernel<10, 64><<<160, 512, 0, stream>>>(W1l, al1l, ar1l, wal1l, war1l, 80,
                                                    W1r, al1r, ar1r, wal1r, war1r);
  prep_wal2_kernel<1, 128><<<16, 512, 0, stream>>>(W2l, al2l, ar2l, wal2l, war2l, 8,
                                                   W2r, al2r, ar2r, wal2r, war2r);
  // CSR build (merged)
  deg2_kernel<<<cdiv(EL, 256) + cdiv(ER, 256), 256, 0, stream>>>(
      dst_lig, degL, EL, cdiv(EL, 256), dst_rec, degR, ER);
  rowptr2_kernel<<<cdiv(NL, 256) + cdiv(NR, 256), 256, 0, stream>>>(
      degL, rpL, curL, cntL, NL, cdiv(NL, 256), degR, rpR, curR, cntR, NR);
  scatter2_kernel<<<cdiv(EL, 256) + cdiv(ER, 256), 256, 0, stream>>>(
      src_lig, dst_lig, curL, srcsL, EL, cdiv(EL, 256), src_rec, dst_rec, curR, srcsR, ER);
  // layer 1 (merged)
  elr10_2_kernel<<<cdiv(NL, 4) + cdiv(NR, 4), 256, 0, stream>>>(
      x_lig, wal1l, war1l, el1L, er1L, NL, cdiv(NL, 4),
      x_rec, wal1r, war1r, el1R, er1R, NR);
  aggr_z10_2_kernel<<<cdiv(NL, 8) + cdiv(NR, 8), 512, 0, stream>>>(
      rpL, degL, srcsL, x_lig, el1L, er1L, zL, NL, cdiv(NL, 8),
      rpR, degR, srcsR, x_rec, el1R, er1R, zR, NR);
  gemm_sumheads2_kernel<<<cdiv(NL, 16) + cdiv(NR, 16), 640, 0, stream>>>(
      zL, W1l, b1l, wal2l, war2l, h1L, el2L, er2L, NL, cdiv(NL, 16),
      zR, W1r, b1r, wal2r, war2r, h1R, el2R, er2R, NR);
  // layer 2 (merged)
  aggr_z1_2_kernel<<<cdiv(NL, 8) + cdiv(NR, 8), 512, 0, stream>>>(
      rpL, degL, srcsL, h1L, el2L, er2L, z2L, NL, cdiv(NL, 8),
      rpR, degR, srcsR, h1R, el2R, er2R, z2R, NR);
  gemm2_readout2_kernel<<<cdiv(NL, 8) + cdiv(NR, 8), 128, 0, stream>>>(
      z2L, W2l, b2l, gid_lig, NL, 0, cdiv(NL, 8),
      z2R, W2r, b2r, gid_rec, NR, 128, readout);

  mlp_kernel<<<32, 128, 0, stream>>>(readout, W_lin1, b_lin1, W_lin2, b_lin2, (float*)d_out);
}

// Round 10
// 503.748 us; speedup vs baseline: 1.2834x; 1.2834x over previous
//
#include <hip/hip_runtime.h>

#define LRELU(x) fmaxf((x), 0.2f*(x))   // identical result to x>0?x:0.2x
#define ZPAD(f) ((f) + 4*((f)>>6))      // 640-float row -> 680 padded (4/head)

static inline int cdiv(int a, int b) { return (a + b - 1) / b; }

// ---------------------------------------------------------------------------
// prep (merged branches): wal[h*64+k] = sum_d W[k, h*DH+d] * al[h*DH+d].
// ---------------------------------------------------------------------------
template<int H, int DH>
__global__ void prep_wal2_kernel(const float* __restrict__ WA, const float* __restrict__ alA,
                                 const float* __restrict__ arA, float* __restrict__ walA,
                                 float* __restrict__ warA, int nbA,
                                 const float* __restrict__ WB, const float* __restrict__ alB,
                                 const float* __restrict__ arB, float* __restrict__ walB,
                                 float* __restrict__ warB) {
  constexpr int K = 64;
  constexpr int HD = H * DH;
  const float *W, *al, *ar; float *wal, *war; int bid;
  if (blockIdx.x < (unsigned)nbA) { W=WA; al=alA; ar=arA; wal=walA; war=warA; bid=blockIdx.x; }
  else { W=WB; al=alB; ar=arB; wal=walB; war=warB; bid=blockIdx.x-nbA; }
  const int wv = threadIdx.x >> 6, lane = threadIdx.x & 63;
  const int o = bid * (blockDim.x >> 6) + wv;
  if (o >= H * K) return;
  const int h = o / K, k = o - h * K;
  float pl = 0.f, pr = 0.f;
#pragma unroll
  for (int j = 0; j < DH / 64; j++) {
    int d = j * 64 + lane;
    float w = W[(size_t)k * HD + h * DH + d];
    pl += w * al[h * DH + d];
    pr += w * ar[h * DH + d];
  }
#pragma unroll
  for (int off = 32; off >= 1; off >>= 1) {
    pl += __shfl_xor(pl, off);
    pr += __shfl_xor(pr, off);
  }
  if (lane == 0) { wal[o] = pl; war[o] = pr; }
}

// ---------------------------------------------------------------------------
// el/er for layer 1 (merged). One wave per node.
// ---------------------------------------------------------------------------
__global__ void elr10_2_kernel(const float* __restrict__ xA, const float* __restrict__ walA,
                               const float* __restrict__ warA, float* __restrict__ elA,
                               float* __restrict__ erA, int NA, int nbA,
                               const float* __restrict__ xB, const float* __restrict__ walB,
                               const float* __restrict__ warB, float* __restrict__ elB,
                               float* __restrict__ erB, int NB) {
  const float *x, *wal, *war; float *el, *er; int N, bid;
  if (blockIdx.x < (unsigned)nbA) { x=xA; wal=walA; war=warA; el=elA; er=erA; N=NA; bid=blockIdx.x; }
  else { x=xB; wal=walB; war=warB; el=elB; er=erB; N=NB; bid=blockIdx.x-nbA; }
  const int wv = threadIdx.x >> 6, lane = threadIdx.x & 63;
  const int n = bid * (blockDim.x >> 6) + wv;
  if (n >= N) return;
  const float xv = x[(size_t)n * 64 + lane];
#pragma unroll
  for (int h = 0; h < 10; h++) {
    float pl = xv * wal[h * 64 + lane];
    float pr = xv * war[h * 64 + lane];
#pragma unroll
    for (int off = 32; off >= 1; off >>= 1) {
      pl += __shfl_xor(pl, off);
      pr += __shfl_xor(pr, off);
    }
    if (lane == 0) { el[(size_t)n * 10 + h] = pl; er[(size_t)n * 10 + h] = pr; }
  }
}

// ---------------------------------------------------------------------------
// CSR build (merged): deg count -> wave-atomic row offsets -> scatter
// ---------------------------------------------------------------------------
__global__ void deg2_kernel(const int* __restrict__ dstA, int* __restrict__ degA, int EA, int nbA,
                            const int* __restrict__ dstB, int* __restrict__ degB, int EB) {
  const int* dst; int* deg; int E, t;
  if (blockIdx.x < (unsigned)nbA) { dst=dstA; deg=degA; E=EA; t=blockIdx.x*256+threadIdx.x; }
  else { dst=dstB; deg=degB; E=EB; t=(blockIdx.x-nbA)*256+threadIdx.x; }
  if (t < E) atomicAdd(&deg[dst[t]], 1);
}

__global__ void rowptr2_kernel(const int* __restrict__ degA, int* __restrict__ rpA,
                               int* __restrict__ curA, int* __restrict__ cntA, int NA, int nbA,
                               const int* __restrict__ degB, int* __restrict__ rpB,
                               int* __restrict__ curB, int* __restrict__ cntB, int NB) {
  const int* deg; int *rp, *cur, *cnt; int N, t;
  if (blockIdx.x < (unsigned)nbA) { deg=degA; rp=rpA; cur=curA; cnt=cntA; N=NA; t=blockIdx.x*256+threadIdx.x; }
  else { deg=degB; rp=rpB; cur=curB; cnt=cntB; N=NB; t=(blockIdx.x-nbA)*256+threadIdx.x; }
  int lane = threadIdx.x & 63;
  int v = (t < N) ? deg[t] : 0;
  int x = v;
#pragma unroll
  for (int off = 1; off < 64; off <<= 1) {
    int y = __shfl_up(x, off);
    if (lane >= off) x += y;
  }
  int total = __shfl(x, 63);
  int base = 0;
  if (lane == 0 && total > 0) base = atomicAdd(cnt, total);
  base = __shfl(base, 0);
  int excl = base + x - v;
  if (t < N) { rp[t] = excl; cur[t] = excl; }
}

__global__ void scatter2_kernel(const int* __restrict__ srcA, const int* __restrict__ dstA,
                                int* __restrict__ curA, int* __restrict__ outA, int EA, int nbA,
                                const int* __restrict__ srcB, const int* __restrict__ dstB,
                                int* __restrict__ curB, int* __restrict__ outB, int EB) {
  const int *src, *dst; int *cur, *out; int E, t;
  if (blockIdx.x < (unsigned)nbA) { src=srcA; dst=dstA; cur=curA; out=outA; E=EA; t=blockIdx.x*256+threadIdx.x; }
  else { src=srcB; dst=dstB; cur=curB; out=outB; E=EB; t=(blockIdx.x-nbA)*256+threadIdx.x; }
  if (t >= E) return;
  int slot = atomicAdd(&cur[dst[t]], 1);
  out[slot] = src[t];
}

// ---------------------------------------------------------------------------
// Layer-1 aggregation (merged): one wave per node, all 10 heads in registers.
// ---------------------------------------------------------------------------
__global__ void aggr_z10_2_kernel(const int* __restrict__ rpA, const int* __restrict__ degA,
                                  const int* __restrict__ srcsA, const float* __restrict__ xA,
                                  const float* __restrict__ elA, const float* __restrict__ erA,
                                  float* __restrict__ zA, int NA, int nbA,
                                  const int* __restrict__ rpB, const int* __restrict__ degB,
                                  const int* __restrict__ srcsB, const float* __restrict__ xB,
                                  const float* __restrict__ elB, const float* __restrict__ erB,
                                  float* __restrict__ zB, int NB) {
  const int *rp, *degp, *srcs; const float *x, *el, *er; float *z; int N, bid;
  if (blockIdx.x < (unsigned)nbA) { rp=rpA; degp=degA; srcs=srcsA; x=xA; el=elA; er=erA; z=zA; N=NA; bid=blockIdx.x; }
  else { rp=rpB; degp=degB; srcs=srcsB; x=xB; el=elB; er=erB; z=zB; N=NB; bid=blockIdx.x-nbA; }
  const int wv = threadIdx.x >> 6, lane = threadIdx.x & 63;
  const int n = bid * (blockDim.x >> 6) + wv;
  if (n >= N) return;
  const int beg = rp[n], dg = degp[n];
  const float2* elv = (const float2*)el;
  const float2* erv = (const float2*)er;
  float ern[10];
#pragma unroll
  for (int j = 0; j < 5; j++) {
    float2 t2 = erv[(size_t)n * 5 + j];
    ern[2 * j] = t2.x; ern[2 * j + 1] = t2.y;
  }
  float den[10], acc[10];
#pragma unroll
  for (int h = 0; h < 10; h++) { den[h] = 0.f; acc[h] = 0.f; }
  int i = 0;
  for (; i + 1 < dg; i += 2) {
    int s0 = srcs[beg + i], s1 = srcs[beg + i + 1];
    float xv0 = x[(size_t)s0 * 64 + lane];
    float xv1 = x[(size_t)s1 * 64 + lane];
    float w0[10], w1[10];
#pragma unroll
    for (int j = 0; j < 5; j++) {
      float2 a = elv[(size_t)s0 * 5 + j];
      float2 c = elv[(size_t)s1 * 5 + j];
      w0[2 * j] = a.x; w0[2 * j + 1] = a.y;
      w1[2 * j] = c.x; w1[2 * j + 1] = c.y;
    }
#pragma unroll
    for (int h = 0; h < 10; h++) {
      float ea = __expf(LRELU(w0[h] + ern[h]));
      float eb = __expf(LRELU(w1[h] + ern[h]));
      den[h] += ea + eb;
      acc[h] += ea * xv0 + eb * xv1;
    }
  }
  if (i < dg) {
    int s0 = srcs[beg + i];
    float xv0 = x[(size_t)s0 * 64 + lane];
    float w0[10];
#pragma unroll
    for (int j = 0; j < 5; j++) {
      float2 a = elv[(size_t)s0 * 5 + j];
      w0[2 * j] = a.x; w0[2 * j + 1] = a.y;
    }
#pragma unroll
    for (int h = 0; h < 10; h++) {
      float ea = __expf(LRELU(w0[h] + ern[h]));
      den[h] += ea;
      acc[h] += ea * xv0;
    }
  }
#pragma unroll
  for (int h = 0; h < 10; h++)
    z[(size_t)n * 640 + h * 64 + lane] = (dg > 0) ? acc[h] / den[h] : 0.f;
}

// ---------------------------------------------------------------------------
// Layer-2 aggregation (merged, H=1): one wave per node over h1sum (64-dim).
// ---------------------------------------------------------------------------
__global__ void aggr_z1_2_kernel(const int* __restrict__ rpA, const int* __restrict__ degA,
                                 const int* __restrict__ srcsA, const float* __restrict__ hA,
                                 const float* __restrict__ elA, const float* __restrict__ erA,
                                 float* __restrict__ zA, int NA, int nbA,
                                 const int* __restrict__ rpB, const int* __restrict__ degB,
                                 const int* __restrict__ srcsB, const float* __restrict__ hB,
                                 const float* __restrict__ elB, const float* __restrict__ erB,
                                 float* __restrict__ zB, int NB) {
  const int *rp, *degp, *srcs; const float *hin, *el, *er; float *z; int N, bid;
  if (blockIdx.x < (unsigned)nbA) { rp=rpA; degp=degA; srcs=srcsA; hin=hA; el=elA; er=erA; z=zA; N=NA; bid=blockIdx.x; }
  else { rp=rpB; degp=degB; srcs=srcsB; hin=hB; el=elB; er=erB; z=zB; N=NB; bid=blockIdx.x-nbA; }
  const int wv = threadIdx.x >> 6, lane = threadIdx.x & 63;
  const int n = bid * (blockDim.x >> 6) + wv;
  if (n >= N) return;
  const int beg = rp[n], dg = degp[n];
  const float ern = er[n];
  float den = 0.f, acc = 0.f;
  int i = 0;
  for (; i + 1 < dg; i += 2) {
    int s0 = srcs[beg + i], s1 = srcs[beg + i + 1];
    float x0 = __expf(LRELU(el[s0] + ern));
    float x1 = __expf(LRELU(el[s1] + ern));
    den += x0 + x1;
    acc += x0 * hin[(size_t)s0 * 64 + lane] + x1 * hin[(size_t)s1 * 64 + lane];
  }
  if (i < dg) {
    int s0 = srcs[beg + i];
    float x0 = __expf(LRELU(el[s0] + ern));
    den += x0;
    acc += x0 * hin[(size_t)s0 * 64 + lane];
  }
  z[(size_t)n * 64 + lane] = (dg > 0) ? acc / den : 0.f;
}

// ---------------------------------------------------------------------------
// Layer-1 GEMM (register-tiled) + relu + head-sum + fused el2/er2.
// 640 thr, 16 nodes/block. Thread = 4 nodes x 4 consecutive outputs (float4 W).
// LDS rows padded 640->680 (+4/head) so the 4 heads/wave hit distinct banks.
// ---------------------------------------------------------------------------
__global__ void gemm_sumheads2_kernel(
    const float* __restrict__ zA, const float* __restrict__ WA, const float* __restrict__ bA,
    const float* __restrict__ wal2A, const float* __restrict__ war2A, float* __restrict__ h1A,
    float* __restrict__ el2A, float* __restrict__ er2A, int NA, int nbA,
    const float* __restrict__ zB, const float* __restrict__ WB, const float* __restrict__ bB,
    const float* __restrict__ wal2B, const float* __restrict__ war2B, float* __restrict__ h1B,
    float* __restrict__ el2B, float* __restrict__ er2B, int NB) {
  constexpr int NPB = 16;
  __shared__ float zs[NPB][680];
  const float *z, *W, *bb, *wal2, *war2; float *h1sum, *el2, *er2; int N, tile;
  if (blockIdx.x < (unsigned)nbA) { z=zA; W=WA; bb=bA; wal2=wal2A; war2=war2A; h1sum=h1A; el2=el2A; er2=er2A; N=NA; tile=blockIdx.x; }
  else { z=zB; W=WB; bb=bB; wal2=wal2B; war2=war2B; h1sum=h1B; el2=el2B; er2=er2B; N=NB; tile=blockIdx.x-nbA; }
  const int f = threadIdx.x;      // 640
  const int n0 = tile * NPB;
  const int pf = ZPAD(f);
#pragma unroll
  for (int i = 0; i < NPB; i++) {
    int n = n0 + i;
    zs[i][pf] = (n < N) ? z[(size_t)n * 640 + f] : 0.f;
  }
  __syncthreads();
  const int f4 = f % 160;         // outputs 4*f4 .. 4*f4+3
  const int ng = f / 160;         // node group: nodes ng*4 .. ng*4+3
  const int head = f4 >> 4;
  const int base = 68 * head;     // padded offset of k=0 within this head
  float acc[4][4];
#pragma unroll
  for (int i = 0; i < 4; i++)
#pragma unroll
    for (int j = 0; j < 4; j++) acc[i][j] = 0.f;
  const float4* W4 = (const float4*)W;
#pragma unroll 4
  for (int k4 = 0; k4 < 16; k4++) {
    float4 zq[4];
#pragma unroll
    for (int i = 0; i < 4; i++)
      zq[i] = *(const float4*)&zs[ng * 4 + i][base + 4 * k4];
#pragma unroll
    for (int j4 = 0; j4 < 4; j4++) {
      const int k = 4 * k4 + j4;
      const float4 w4 = W4[(size_t)k * 160 + f4];
#pragma unroll
      for (int i = 0; i < 4; i++) {
        const float zv = j4 == 0 ? zq[i].x : j4 == 1 ? zq[i].y : j4 == 2 ? zq[i].z : zq[i].w;
        acc[i][0] = fmaf(zv, w4.x, acc[i][0]);
        acc[i][1] = fmaf(zv, w4.y, acc[i][1]);
        acc[i][2] = fmaf(zv, w4.z, acc[i][2]);
        acc[i][3] = fmaf(zv, w4.w, acc[i][3]);
      }
    }
  }
  const float4 b4 = ((const float4*)bb)[f4];
  __syncthreads();
#pragma unroll
  for (int i = 0; i < 4; i++) {
    float* row = &zs[ng * 4 + i][ZPAD(4 * f4)];   // 4 consecutive (same head)
    row[0] = fmaxf(acc[i][0] + b4.x, 0.f);
    row[1] = fmaxf(acc[i][1] + b4.y, 0.f);
    row[2] = fmaxf(acc[i][2] + b4.z, 0.f);
    row[3] = fmaxf(acc[i][3] + b4.w, 0.f);
  }
  __syncthreads();
  const int lane = threadIdx.x & 63;
  for (int idx = threadIdx.x; idx < NPB * 64; idx += 640) {
    const int i = idx >> 6, d = idx & 63;
    float s = 0.f;
#pragma unroll
    for (int h = 0; h < 10; h++) s += zs[i][68 * h + d];
    const int n = n0 + i;
    float pl = s * wal2[d], pr = s * war2[d];
#pragma unroll
    for (int off = 32; off >= 1; off >>= 1) {
      pl += __shfl_xor(pl, off);
      pr += __shfl_xor(pr, off);
    }
    if (n < N) {
      h1sum[(size_t)n * 64 + d] = s;
      if (lane == 0) { el2[n] = pl; er2[n] = pr; }
    }
  }
}

// ---------------------------------------------------------------------------
// Layer-2 GEMM + relu + block-local segment-max, then ONE atomicMax per
// contiguous gid-run per column (gid is sorted). 128 thr, 16 nodes/block.
// Thread = column f for all 16 nodes (coalesced atomics, lane-consecutive).
// ---------------------------------------------------------------------------
__global__ void gemm2_readout3_kernel(
    const float* __restrict__ zA, const float* __restrict__ WA, const float* __restrict__ bA,
    const int* __restrict__ gidA, int NA, int coA, int nbA,
    const float* __restrict__ zB, const float* __restrict__ WB, const float* __restrict__ bB,
    const int* __restrict__ gidB, int NB, int coB,
    float* __restrict__ readout) {
  constexpr int NPB = 16;
  __shared__ float zs[NPB][64];
  __shared__ float vals[NPB][128];
  __shared__ int gids[NPB];
  const float *z, *W, *bb; const int* gid; int N, colOff, tile;
  if (blockIdx.x < (unsigned)nbA) { z=zA; W=WA; bb=bA; gid=gidA; N=NA; colOff=coA; tile=blockIdx.x; }
  else { z=zB; W=WB; bb=bB; gid=gidB; N=NB; colOff=coB; tile=blockIdx.x-nbA; }
  const int f = threadIdx.x;      // 128
  const int n0 = tile * NPB;
  for (int idx = f; idx < NPB * 64; idx += 128) {
    int i = idx >> 6, k = idx & 63;
    int n = n0 + i;
    zs[i][k] = (n < N) ? z[(size_t)n * 64 + k] : 0.f;
  }
  if (f < NPB) gids[f] = (n0 + f < N) ? gid[n0 + f] : -1;
  __syncthreads();
  float acc[NPB];
#pragma unroll
  for (int i = 0; i < NPB; i++) acc[i] = 0.f;
#pragma unroll 4
  for (int k4 = 0; k4 < 16; k4++) {
    const float w0 = W[(size_t)(4 * k4 + 0) * 128 + f];
    const float w1 = W[(size_t)(4 * k4 + 1) * 128 + f];
    const float w2 = W[(size_t)(4 * k4 + 2) * 128 + f];
    const float w3 = W[(size_t)(4 * k4 + 3) * 128 + f];
#pragma unroll
    for (int i = 0; i < NPB; i++) {
      float4 zq = *(const float4*)&zs[i][4 * k4];
      acc[i] = fmaf(zq.x, w0, fmaf(zq.y, w1, fmaf(zq.z, w2, fmaf(zq.w, w3, acc[i]))));
    }
  }
  const float bbf = bb[f];
#pragma unroll
  for (int i = 0; i < NPB; i++) vals[i][f] = fmaxf(acc[i] + bbf, 0.f);
  __syncthreads();
  // run-merge over sorted gids; one atomic per run per column
  float run = 0.f;
  int curg = -1;
#pragma unroll
  for (int i = 0; i < NPB; i++) {
    int g = gids[i];
    if (g < 0) break;
    if (g != curg) {
      if (curg >= 0)
        atomicMax((unsigned int*)&readout[curg * 256 + colOff + f], __float_as_uint(run));
      curg = g;
      run = 0.f;
    }
    run = fmaxf(run, vals[i][f]);
  }
  if (curg >= 0)
    atomicMax((unsigned int*)&readout[curg * 256 + colOff + f], __float_as_uint(run));
}

// MLP: relu(concat @ W1 + b1) @ W2 + b2 -> relu -> out[32]
__global__ void mlp_kernel(const float* __restrict__ readout, const float* __restrict__ W1,
                           const float* __restrict__ b1, const float* __restrict__ W2,
                           const float* __restrict__ b2, float* __restrict__ out) {
  int b = blockIdx.x;   // 32
  int j = threadIdx.x;  // 128
  __shared__ float rs[256];
  rs[j] = readout[b * 256 + j];
  rs[j + 128] = readout[b * 256 + 128 + j];
  __syncthreads();
  float acc = b1[j];
#pragma unroll 8
  for (int k = 0; k < 256; k++) acc += rs[k] * W1[k * 128 + j];
  acc = fmaxf(acc, 0.f);
  float p = acc * W2[j];
#pragma unroll
  for (int off = 32; off >= 1; off >>= 1) p += __shfl_xor(p, off);
  __shared__ float wsum[2];
  if ((threadIdx.x & 63) == 0) wsum[threadIdx.x >> 6] = p;
  __syncthreads();
  if (threadIdx.x == 0) {
    float s = wsum[0] + wsum[1] + b2[0];
    out[b] = fmaxf(s, 0.f);
  }
}

// ---------------------------------------------------------------------------
extern "C" void kernel_launch(void* const* d_in, const int* in_sizes, int n_in,
                              void* d_out, int out_size, void* d_ws, size_t ws_size,
                              hipStream_t stream) {
  const float* x_lig = (const float*)d_in[0];
  const int* src_lig = (const int*)d_in[1];
  const int* dst_lig = (const int*)d_in[2];
  const int* gid_lig = (const int*)d_in[3];
  const float* x_rec = (const float*)d_in[4];
  const int* src_rec = (const int*)d_in[5];
  const int* dst_rec = (const int*)d_in[6];
  const int* gid_rec = (const int*)d_in[7];
  const float* W1l = (const float*)d_in[8];
  const float* al1l = (const float*)d_in[9];
  const float* ar1l = (const float*)d_in[10];
  const float* b1l = (const float*)d_in[11];
  const float* W2l = (const float*)d_in[12];
  const float* al2l = (const float*)d_in[13];
  const float* ar2l = (const float*)d_in[14];
  const float* b2l = (const float*)d_in[15];
  const float* W1r = (const float*)d_in[16];
  const float* al1r = (const float*)d_in[17];
  const float* ar1r = (const float*)d_in[18];
  const float* b1r = (const float*)d_in[19];
  const float* W2r = (const float*)d_in[20];
  const float* al2r = (const float*)d_in[21];
  const float* ar2r = (const float*)d_in[22];
  const float* b2r = (const float*)d_in[23];
  const float* W_lin1 = (const float*)d_in[24];
  const float* b_lin1 = (const float*)d_in[25];
  const float* W_lin2 = (const float*)d_in[26];
  const float* b_lin2 = (const float*)d_in[27];

  const int NL = 10000, EL = 80000, NR = 30000, ER = 480000;
  float* p = (float*)d_ws;
  float* zL = p;      p += (size_t)NL * 640;
  float* zR = p;      p += (size_t)NR * 640;
  float* z2L = p;     p += (size_t)NL * 64;
  float* z2R = p;     p += (size_t)NR * 64;
  float* h1L = p;     p += (size_t)NL * 64;
  float* h1R = p;     p += (size_t)NR * 64;
  float* el1L = p;    p += (size_t)NL * 10;
  float* er1L = p;    p += (size_t)NL * 10;
  float* el1R = p;    p += (size_t)NR * 10;
  float* er1R = p;    p += (size_t)NR * 10;
  float* el2L = p;    p += NL;
  float* er2L = p;    p += NL;
  float* el2R = p;    p += NR;
  float* er2R = p;    p += NR;
  float* wal1l = p;   p += 640;
  float* war1l = p;   p += 640;
  float* wal1r = p;   p += 640;
  float* war1r = p;   p += 640;
  float* wal2l = p;   p += 64;
  float* war2l = p;   p += 64;
  float* wal2r = p;   p += 64;
  float* war2r = p;   p += 64;
  float* zero_base = p;
  float* readout = p; p += 32 * 256;
  int* ip = (int*)p;
  int* degL = ip;     ip += NL;
  int* cntL = ip;     ip += 1;
  int* degR = ip;     ip += NR;
  int* cntR = ip;     ip += 1;
  size_t zero_bytes = (size_t)((char*)ip - (char*)zero_base);
  int* rpL = ip;      ip += NL;
  int* curL = ip;     ip += NL;
  int* srcsL = ip;    ip += EL;
  int* rpR = ip;      ip += NR;
  int* curR = ip;     ip += NR;
  int* srcsR = ip;    ip += ER;

  hipMemsetAsync(zero_base, 0, zero_bytes, stream);

  prep_wal2_kernel<10, 64><<<160, 512, 0, stream>>>(W1l, al1l, ar1l, wal1l, war1l, 80,
                                                    W1r, al1r, ar1r, wal1r, war1r);
  prep_wal2_kernel<1, 128><<<16, 512, 0, stream>>>(W2l, al2l, ar2l, wal2l, war2l, 8,
                                                   W2r, al2r, ar2r, wal2r, war2r);
  deg2_kernel<<<cdiv(EL, 256) + cdiv(ER, 256), 256, 0, stream>>>(
      dst_lig, degL, EL, cdiv(EL, 256), dst_rec, degR, ER);
  rowptr2_kernel<<<cdiv(NL, 256) + cdiv(NR, 256), 256, 0, stream>>>(
      degL, rpL, curL, cntL, NL, cdiv(NL, 256), degR, rpR, curR, cntR, NR);
  scatter2_kernel<<<cdiv(EL, 256) + cdiv(ER, 256), 256, 0, stream>>>(
      src_lig, dst_lig, curL, srcsL, EL, cdiv(EL, 256), src_rec, dst_rec, curR, srcsR, ER);
  elr10_2_kernel<<<cdiv(NL, 4) + cdiv(NR, 4), 256, 0, stream>>>(
      x_lig, wal1l, war1l, el1L, er1L, NL, cdiv(NL, 4),
      x_rec, wal1r, war1r, el1R, er1R, NR);
  aggr_z10_2_kernel<<<cdiv(NL, 8) + cdiv(NR, 8), 512, 0, stream>>>(
      rpL, degL, srcsL, x_lig, el1L, er1L, zL, NL, cdiv(NL, 8),
      rpR, degR, srcsR, x_rec, el1R, er1R, zR, NR);
  gemm_sumheads2_kernel<<<cdiv(NL, 16) + cdiv(NR, 16), 640, 0, stream>>>(
      zL, W1l, b1l, wal2l, war2l, h1L, el2L, er2L, NL, cdiv(NL, 16),
      zR, W1r, b1r, wal2r, war2r, h1R, el2R, er2R, NR);
  aggr_z1_2_kernel<<<cdiv(NL, 8) + cdiv(NR, 8), 512, 0, stream>>>(
      rpL, degL, srcsL, h1L, el2L, er2L, z2L, NL, cdiv(NL, 8),
      rpR, degR, srcsR, h1R, el2R, er2R, z2R, NR);
  gemm2_readout3_kernel<<<cdiv(NL, 16) + cdiv(NR, 16), 128, 0, stream>>>(
      z2L, W2l, b2l, gid_lig, NL, 0, cdiv(NL, 16),
      z2R, W2r, b2r, gid_rec, NR, 128, readout);

  mlp_kernel<<<32, 128, 0, stream>>>(readout, W_lin1, b_lin1, W_lin2, b_lin2, (float*)d_out);
}

// Round 11
// 494.643 us; speedup vs baseline: 1.3071x; 1.0184x over previous
//
#include <hip/hip_runtime.h>

#define LRELU(x) fmaxf((x), 0.2f*(x))   // identical result to x>0?x:0.2x
#define ZPAD(f) ((f) + 4*((f)>>6))      // 640-float row -> 680 padded (4/head)

static inline int cdiv(int a, int b) { return (a + b - 1) / b; }

// ---------------------------------------------------------------------------
// prep (merged branches): wal[h*64+k] = sum_d W[k, h*DH+d] * al[h*DH+d].
// ---------------------------------------------------------------------------
template<int H, int DH>
__global__ void prep_wal2_kernel(const float* __restrict__ WA, const float* __restrict__ alA,
                                 const float* __restrict__ arA, float* __restrict__ walA,
                                 float* __restrict__ warA, int nbA,
                                 const float* __restrict__ WB, const float* __restrict__ alB,
                                 const float* __restrict__ arB, float* __restrict__ walB,
                                 float* __restrict__ warB) {
  constexpr int K = 64;
  constexpr int HD = H * DH;
  const float *W, *al, *ar; float *wal, *war; int bid;
  if (blockIdx.x < (unsigned)nbA) { W=WA; al=alA; ar=arA; wal=walA; war=warA; bid=blockIdx.x; }
  else { W=WB; al=alB; ar=arB; wal=walB; war=warB; bid=blockIdx.x-nbA; }
  const int wv = threadIdx.x >> 6, lane = threadIdx.x & 63;
  const int o = bid * (blockDim.x >> 6) + wv;
  if (o >= H * K) return;
  const int h = o / K, k = o - h * K;
  float pl = 0.f, pr = 0.f;
#pragma unroll
  for (int j = 0; j < DH / 64; j++) {
    int d = j * 64 + lane;
    float w = W[(size_t)k * HD + h * DH + d];
    pl += w * al[h * DH + d];
    pr += w * ar[h * DH + d];
  }
#pragma unroll
  for (int off = 32; off >= 1; off >>= 1) {
    pl += __shfl_xor(pl, off);
    pr += __shfl_xor(pr, off);
  }
  if (lane == 0) { wal[o] = pl; war[o] = pr; }
}

// ---------------------------------------------------------------------------
// el/er for layer 1 (merged). One wave per node.
// ---------------------------------------------------------------------------
__global__ void elr10_2_kernel(const float* __restrict__ xA, const float* __restrict__ walA,
                               const float* __restrict__ warA, float* __restrict__ elA,
                               float* __restrict__ erA, int NA, int nbA,
                               const float* __restrict__ xB, const float* __restrict__ walB,
                               const float* __restrict__ warB, float* __restrict__ elB,
                               float* __restrict__ erB, int NB) {
  const float *x, *wal, *war; float *el, *er; int N, bid;
  if (blockIdx.x < (unsigned)nbA) { x=xA; wal=walA; war=warA; el=elA; er=erA; N=NA; bid=blockIdx.x; }
  else { x=xB; wal=walB; war=warB; el=elB; er=erB; N=NB; bid=blockIdx.x-nbA; }
  const int wv = threadIdx.x >> 6, lane = threadIdx.x & 63;
  const int n = bid * (blockDim.x >> 6) + wv;
  if (n >= N) return;
  const float xv = x[(size_t)n * 64 + lane];
#pragma unroll
  for (int h = 0; h < 10; h++) {
    float pl = xv * wal[h * 64 + lane];
    float pr = xv * war[h * 64 + lane];
#pragma unroll
    for (int off = 32; off >= 1; off >>= 1) {
      pl += __shfl_xor(pl, off);
      pr += __shfl_xor(pr, off);
    }
    if (lane == 0) { el[(size_t)n * 10 + h] = pl; er[(size_t)n * 10 + h] = pr; }
  }
}

// ---------------------------------------------------------------------------
// CSR build (merged): deg count -> wave-atomic row offsets -> scatter+exp
// ---------------------------------------------------------------------------
__global__ void deg2_kernel(const int* __restrict__ dstA, int* __restrict__ degA, int EA, int nbA,
                            const int* __restrict__ dstB, int* __restrict__ degB, int EB) {
  const int* dst; int* deg; int E, t;
  if (blockIdx.x < (unsigned)nbA) { dst=dstA; deg=degA; E=EA; t=blockIdx.x*256+threadIdx.x; }
  else { dst=dstB; deg=degB; E=EB; t=(blockIdx.x-nbA)*256+threadIdx.x; }
  if (t < E) atomicAdd(&deg[dst[t]], 1);
}

__global__ void rowptr2_kernel(const int* __restrict__ degA, int* __restrict__ rpA,
                               int* __restrict__ curA, int* __restrict__ cntA, int NA, int nbA,
                               const int* __restrict__ degB, int* __restrict__ rpB,
                               int* __restrict__ curB, int* __restrict__ cntB, int NB) {
  const int* deg; int *rp, *cur, *cnt; int N, t;
  if (blockIdx.x < (unsigned)nbA) { deg=degA; rp=rpA; cur=curA; cnt=cntA; N=NA; t=blockIdx.x*256+threadIdx.x; }
  else { deg=degB; rp=rpB; cur=curB; cnt=cntB; N=NB; t=(blockIdx.x-nbA)*256+threadIdx.x; }
  int lane = threadIdx.x & 63;
  int v = (t < N) ? deg[t] : 0;
  int x = v;
#pragma unroll
  for (int off = 1; off < 64; off <<= 1) {
    int y = __shfl_up(x, off);
    if (lane >= off) x += y;
  }
  int total = __shfl(x, 63);
  int base = 0;
  if (lane == 0 && total > 0) base = atomicAdd(cnt, total);
  base = __shfl(base, 0);
  int excl = base + x - v;
  if (t < N) { rp[t] = excl; cur[t] = excl; }
}

// scatter + per-edge exp: ex[slot*10+h] = exp(lrelu(el[s,h]+er[d,h]))
// (computed ONCE per edge here, instead of 64x redundantly in the aggr wave)
__global__ void scatter_ex2_kernel(
    const int* __restrict__ srcA, const int* __restrict__ dstA, int* __restrict__ curA,
    int* __restrict__ outA, const float* __restrict__ elA, const float* __restrict__ erA,
    float* __restrict__ exA, int EA, int nbA,
    const int* __restrict__ srcB, const int* __restrict__ dstB, int* __restrict__ curB,
    int* __restrict__ outB, const float* __restrict__ elB, const float* __restrict__ erB,
    float* __restrict__ exB, int EB) {
  const int *src, *dst; int *cur, *out; const float *el, *er; float *ex; int E, t;
  if (blockIdx.x < (unsigned)nbA) { src=srcA; dst=dstA; cur=curA; out=outA; el=elA; er=erA; ex=exA; E=EA; t=blockIdx.x*256+threadIdx.x; }
  else { src=srcB; dst=dstB; cur=curB; out=outB; el=elB; er=erB; ex=exB; E=EB; t=(blockIdx.x-nbA)*256+threadIdx.x; }
  if (t >= E) return;
  const int s = src[t], d = dst[t];
  const int slot = atomicAdd(&cur[d], 1);
  out[slot] = s;
  const float2* elv = (const float2*)el;
  const float2* erv = (const float2*)er;
  float2* exv = (float2*)ex;
#pragma unroll
  for (int j = 0; j < 5; j++) {
    float2 a = elv[(size_t)s * 5 + j];
    float2 b = erv[(size_t)d * 5 + j];
    float2 e;
    e.x = __expf(LRELU(a.x + b.x));
    e.y = __expf(LRELU(a.y + b.y));
    exv[(size_t)slot * 5 + j] = e;
  }
}

// ---------------------------------------------------------------------------
// Layer-1 aggregation (merged): one wave per node, 10 heads in registers.
// Per edge: 1 srcs load + 1 x-row load + 5 float2 ex loads + 10 add + 10 FMA.
// ---------------------------------------------------------------------------
__global__ void aggr_z10_2_kernel(const int* __restrict__ rpA, const int* __restrict__ degA,
                                  const int* __restrict__ srcsA, const float* __restrict__ xA,
                                  const float* __restrict__ exA, float* __restrict__ zA,
                                  int NA, int nbA,
                                  const int* __restrict__ rpB, const int* __restrict__ degB,
                                  const int* __restrict__ srcsB, const float* __restrict__ xB,
                                  const float* __restrict__ exB, float* __restrict__ zB, int NB) {
  const int *rp, *degp, *srcs; const float *x, *ex; float *z; int N, bid;
  if (blockIdx.x < (unsigned)nbA) { rp=rpA; degp=degA; srcs=srcsA; x=xA; ex=exA; z=zA; N=NA; bid=blockIdx.x; }
  else { rp=rpB; degp=degB; srcs=srcsB; x=xB; ex=exB; z=zB; N=NB; bid=blockIdx.x-nbA; }
  const int wv = threadIdx.x >> 6, lane = threadIdx.x & 63;
  const int n = bid * (blockDim.x >> 6) + wv;
  if (n >= N) return;
  const int beg = rp[n], dg = degp[n];
  const float2* exv = (const float2*)ex;
  float den[10], acc[10];
#pragma unroll
  for (int h = 0; h < 10; h++) { den[h] = 0.f; acc[h] = 0.f; }
  int i = 0;
  for (; i + 1 < dg; i += 2) {
    int s0 = srcs[beg + i], s1 = srcs[beg + i + 1];
    float xv0 = x[(size_t)s0 * 64 + lane];
    float xv1 = x[(size_t)s1 * 64 + lane];
    float e0[10], e1[10];
#pragma unroll
    for (int j = 0; j < 5; j++) {
      float2 a = exv[(size_t)(beg + i) * 5 + j];
      float2 c = exv[(size_t)(beg + i + 1) * 5 + j];
      e0[2 * j] = a.x; e0[2 * j + 1] = a.y;
      e1[2 * j] = c.x; e1[2 * j + 1] = c.y;
    }
#pragma unroll
    for (int h = 0; h < 10; h++) {
      den[h] += e0[h] + e1[h];
      acc[h] = fmaf(e0[h], xv0, fmaf(e1[h], xv1, acc[h]));
    }
  }
  if (i < dg) {
    int s0 = srcs[beg + i];
    float xv0 = x[(size_t)s0 * 64 + lane];
#pragma unroll
    for (int j = 0; j < 5; j++) {
      float2 a = exv[(size_t)(beg + i) * 5 + j];
      den[2 * j] += a.x;
      den[2 * j + 1] += a.y;
      acc[2 * j] = fmaf(a.x, xv0, acc[2 * j]);
      acc[2 * j + 1] = fmaf(a.y, xv0, acc[2 * j + 1]);
    }
  }
#pragma unroll
  for (int h = 0; h < 10; h++)
    z[(size_t)n * 640 + h * 64 + lane] = (dg > 0) ? acc[h] / den[h] : 0.f;
}

// ---------------------------------------------------------------------------
// Layer-2 aggregation (merged, H=1): one wave per node over h1sum (64-dim).
// ---------------------------------------------------------------------------
__global__ void aggr_z1_2_kernel(const int* __restrict__ rpA, const int* __restrict__ degA,
                                 const int* __restrict__ srcsA, const float* __restrict__ hA,
                                 const float* __restrict__ elA, const float* __restrict__ erA,
                                 float* __restrict__ zA, int NA, int nbA,
                                 const int* __restrict__ rpB, const int* __restrict__ degB,
                                 const int* __restrict__ srcsB, const float* __restrict__ hB,
                                 const float* __restrict__ elB, const float* __restrict__ erB,
                                 float* __restrict__ zB, int NB) {
  const int *rp, *degp, *srcs; const float *hin, *el, *er; float *z; int N, bid;
  if (blockIdx.x < (unsigned)nbA) { rp=rpA; degp=degA; srcs=srcsA; hin=hA; el=elA; er=erA; z=zA; N=NA; bid=blockIdx.x; }
  else { rp=rpB; degp=degB; srcs=srcsB; hin=hB; el=elB; er=erB; z=zB; N=NB; bid=blockIdx.x-nbA; }
  const int wv = threadIdx.x >> 6, lane = threadIdx.x & 63;
  const int n = bid * (blockDim.x >> 6) + wv;
  if (n >= N) return;
  const int beg = rp[n], dg = degp[n];
  const float ern = er[n];
  float den = 0.f, acc = 0.f;
  int i = 0;
  for (; i + 1 < dg; i += 2) {
    int s0 = srcs[beg + i], s1 = srcs[beg + i + 1];
    float x0 = __expf(LRELU(el[s0] + ern));
    float x1 = __expf(LRELU(el[s1] + ern));
    den += x0 + x1;
    acc += x0 * hin[(size_t)s0 * 64 + lane] + x1 * hin[(size_t)s1 * 64 + lane];
  }
  if (i < dg) {
    int s0 = srcs[beg + i];
    float x0 = __expf(LRELU(el[s0] + ern));
    den += x0;
    acc += x0 * hin[(size_t)s0 * 64 + lane];
  }
  z[(size_t)n * 64 + lane] = (dg > 0) ? acc / den : 0.f;
}

// ---------------------------------------------------------------------------
// Layer-1 GEMM (register-tiled) + relu + head-sum + fused el2/er2.
// ---------------------------------------------------------------------------
__global__ void gemm_sumheads2_kernel(
    const float* __restrict__ zA, const float* __restrict__ WA, const float* __restrict__ bA,
    const float* __restrict__ wal2A, const float* __restrict__ war2A, float* __restrict__ h1A,
    float* __restrict__ el2A, float* __restrict__ er2A, int NA, int nbA,
    const float* __restrict__ zB, const float* __restrict__ WB, const float* __restrict__ bB,
    const float* __restrict__ wal2B, const float* __restrict__ war2B, float* __restrict__ h1B,
    float* __restrict__ el2B, float* __restrict__ er2B, int NB) {
  constexpr int NPB = 16;
  __shared__ float zs[NPB][680];
  const float *z, *W, *bb, *wal2, *war2; float *h1sum, *el2, *er2; int N, tile;
  if (blockIdx.x < (unsigned)nbA) { z=zA; W=WA; bb=bA; wal2=wal2A; war2=war2A; h1sum=h1A; el2=el2A; er2=er2A; N=NA; tile=blockIdx.x; }
  else { z=zB; W=WB; bb=bB; wal2=wal2B; war2=war2B; h1sum=h1B; el2=el2B; er2=er2B; N=NB; tile=blockIdx.x-nbA; }
  const int f = threadIdx.x;      // 640
  const int n0 = tile * NPB;
  const int pf = ZPAD(f);
#pragma unroll
  for (int i = 0; i < NPB; i++) {
    int n = n0 + i;
    zs[i][pf] = (n < N) ? z[(size_t)n * 640 + f] : 0.f;
  }
  __syncthreads();
  const int f4 = f % 160;         // outputs 4*f4 .. 4*f4+3
  const int ng = f / 160;         // node group: nodes ng*4 .. ng*4+3
  const int head = f4 >> 4;
  const int base = 68 * head;     // padded offset of k=0 within this head
  float acc[4][4];
#pragma unroll
  for (int i = 0; i < 4; i++)
#pragma unroll
    for (int j = 0; j < 4; j++) acc[i][j] = 0.f;
  const float4* W4 = (const float4*)W;
#pragma unroll 4
  for (int k4 = 0; k4 < 16; k4++) {
    float4 zq[4];
#pragma unroll
    for (int i = 0; i < 4; i++)
      zq[i] = *(const float4*)&zs[ng * 4 + i][base + 4 * k4];
#pragma unroll
    for (int j4 = 0; j4 < 4; j4++) {
      const int k = 4 * k4 + j4;
      const float4 w4 = W4[(size_t)k * 160 + f4];
#pragma unroll
      for (int i = 0; i < 4; i++) {
        const float zv = j4 == 0 ? zq[i].x : j4 == 1 ? zq[i].y : j4 == 2 ? zq[i].z : zq[i].w;
        acc[i][0] = fmaf(zv, w4.x, acc[i][0]);
        acc[i][1] = fmaf(zv, w4.y, acc[i][1]);
        acc[i][2] = fmaf(zv, w4.z, acc[i][2]);
        acc[i][3] = fmaf(zv, w4.w, acc[i][3]);
      }
    }
  }
  const float4 b4 = ((const float4*)bb)[f4];
  __syncthreads();
#pragma unroll
  for (int i = 0; i < 4; i++) {
    float* row = &zs[ng * 4 + i][ZPAD(4 * f4)];   // 4 consecutive (same head)
    row[0] = fmaxf(acc[i][0] + b4.x, 0.f);
    row[1] = fmaxf(acc[i][1] + b4.y, 0.f);
    row[2] = fmaxf(acc[i][2] + b4.z, 0.f);
    row[3] = fmaxf(acc[i][3] + b4.w, 0.f);
  }
  __syncthreads();
  const int lane = threadIdx.x & 63;
  for (int idx = threadIdx.x; idx < NPB * 64; idx += 640) {
    const int i = idx >> 6, d = idx & 63;
    float s = 0.f;
#pragma unroll
    for (int h = 0; h < 10; h++) s += zs[i][68 * h + d];
    const int n = n0 + i;
    float pl = s * wal2[d], pr = s * war2[d];
#pragma unroll
    for (int off = 32; off >= 1; off >>= 1) {
      pl += __shfl_xor(pl, off);
      pr += __shfl_xor(pr, off);
    }
    if (n < N) {
      h1sum[(size_t)n * 64 + d] = s;
      if (lane == 0) { el2[n] = pl; er2[n] = pr; }
    }
  }
}

// ---------------------------------------------------------------------------
// Layer-2 GEMM + relu + block-local segment-max, one atomic per gid-run/col.
// ---------------------------------------------------------------------------
__global__ void gemm2_readout3_kernel(
    const float* __restrict__ zA, const float* __restrict__ WA, const float* __restrict__ bA,
    const int* __restrict__ gidA, int NA, int coA, int nbA,
    const float* __restrict__ zB, const float* __restrict__ WB, const float* __restrict__ bB,
    const int* __restrict__ gidB, int NB, int coB,
    float* __restrict__ readout) {
  constexpr int NPB = 16;
  __shared__ float zs[NPB][64];
  __shared__ float vals[NPB][128];
  __shared__ int gids[NPB];
  const float *z, *W, *bb; const int* gid; int N, colOff, tile;
  if (blockIdx.x < (unsigned)nbA) { z=zA; W=WA; bb=bA; gid=gidA; N=NA; colOff=coA; tile=blockIdx.x; }
  else { z=zB; W=WB; bb=bB; gid=gidB; N=NB; colOff=coB; tile=blockIdx.x-nbA; }
  const int f = threadIdx.x;      // 128
  const int n0 = tile * NPB;
  for (int idx = f; idx < NPB * 64; idx += 128) {
    int i = idx >> 6, k = idx & 63;
    int n = n0 + i;
    zs[i][k] = (n < N) ? z[(size_t)n * 64 + k] : 0.f;
  }
  if (f < NPB) gids[f] = (n0 + f < N) ? gid[n0 + f] : -1;
  __syncthreads();
  float acc[NPB];
#pragma unroll
  for (int i = 0; i < NPB; i++) acc[i] = 0.f;
#pragma unroll 4
  for (int k4 = 0; k4 < 16; k4++) {
    const float w0 = W[(size_t)(4 * k4 + 0) * 128 + f];
    const float w1 = W[(size_t)(4 * k4 + 1) * 128 + f];
    const float w2 = W[(size_t)(4 * k4 + 2) * 128 + f];
    const float w3 = W[(size_t)(4 * k4 + 3) * 128 + f];
#pragma unroll
    for (int i = 0; i < NPB; i++) {
      float4 zq = *(const float4*)&zs[i][4 * k4];
      acc[i] = fmaf(zq.x, w0, fmaf(zq.y, w1, fmaf(zq.z, w2, fmaf(zq.w, w3, acc[i]))));
    }
  }
  const float bbf = bb[f];
#pragma unroll
  for (int i = 0; i < NPB; i++) vals[i][f] = fmaxf(acc[i] + bbf, 0.f);
  __syncthreads();
  float run = 0.f;
  int curg = -1;
#pragma unroll
  for (int i = 0; i < NPB; i++) {
    int g = gids[i];
    if (g < 0) break;
    if (g != curg) {
      if (curg >= 0)
        atomicMax((unsigned int*)&readout[curg * 256 + colOff + f], __float_as_uint(run));
      curg = g;
      run = 0.f;
    }
    run = fmaxf(run, vals[i][f]);
  }
  if (curg >= 0)
    atomicMax((unsigned int*)&readout[curg * 256 + colOff + f], __float_as_uint(run));
}

// MLP: relu(concat @ W1 + b1) @ W2 + b2 -> relu -> out[32]
__global__ void mlp_kernel(const float* __restrict__ readout, const float* __restrict__ W1,
                           const float* __restrict__ b1, const float* __restrict__ W2,
                           const float* __restrict__ b2, float* __restrict__ out) {
  int b = blockIdx.x;   // 32
  int j = threadIdx.x;  // 128
  __shared__ float rs[256];
  rs[j] = readout[b * 256 + j];
  rs[j + 128] = readout[b * 256 + 128 + j];
  __syncthreads();
  float acc = b1[j];
#pragma unroll 8
  for (int k = 0; k < 256; k++) acc += rs[k] * W1[k * 128 + j];
  acc = fmaxf(acc, 0.f);
  float p = acc * W2[j];
#pragma unroll
  for (int off = 32; off >= 1; off >>= 1) p += __shfl_xor(p, off);
  __shared__ float wsum[2];
  if ((threadIdx.x & 63) == 0) wsum[threadIdx.x >> 6] = p;
  __syncthreads();
  if (threadIdx.x == 0) {
    float s = wsum[0] + wsum[1] + b2[0];
    out[b] = fmaxf(s, 0.f);
  }
}

// ---------------------------------------------------------------------------
extern "C" void kernel_launch(void* const* d_in, const int* in_sizes, int n_in,
                              void* d_out, int out_size, void* d_ws, size_t ws_size,
                              hipStream_t stream) {
  const float* x_lig = (const float*)d_in[0];
  const int* src_lig = (const int*)d_in[1];
  const int* dst_lig = (const int*)d_in[2];
  const int* gid_lig = (const int*)d_in[3];
  const float* x_rec = (const float*)d_in[4];
  const int* src_rec = (const int*)d_in[5];
  const int* dst_rec = (const int*)d_in[6];
  const int* gid_rec = (const int*)d_in[7];
  const float* W1l = (const float*)d_in[8];
  const float* al1l = (const float*)d_in[9];
  const float* ar1l = (const float*)d_in[10];
  const float* b1l = (const float*)d_in[11];
  const float* W2l = (const float*)d_in[12];
  const float* al2l = (const float*)d_in[13];
  const float* ar2l = (const float*)d_in[14];
  const float* b2l = (const float*)d_in[15];
  const float* W1r = (const float*)d_in[16];
  const float* al1r = (const float*)d_in[17];
  const float* ar1r = (const float*)d_in[18];
  const float* b1r = (const float*)d_in[19];
  const float* W2r = (const float*)d_in[20];
  const float* al2r = (const float*)d_in[21];
  const float* ar2r = (const float*)d_in[22];
  const float* b2r = (const float*)d_in[23];
  const float* W_lin1 = (const float*)d_in[24];
  const float* b_lin1 = (const float*)d_in[25];
  const float* W_lin2 = (const float*)d_in[26];
  const float* b_lin2 = (const float*)d_in[27];

  const int NL = 10000, EL = 80000, NR = 30000, ER = 480000;
  float* p = (float*)d_ws;
  float* zL = p;      p += (size_t)NL * 640;
  float* zR = p;      p += (size_t)NR * 640;
  float* ex1L = p;    p += (size_t)EL * 10;
  float* ex1R = p;    p += (size_t)ER * 10;
  float* z2L = p;     p += (size_t)NL * 64;
  float* z2R = p;     p += (size_t)NR * 64;
  float* h1L = p;     p += (size_t)NL * 64;
  float* h1R = p;     p += (size_t)NR * 64;
  float* el1L = p;    p += (size_t)NL * 10;
  float* er1L = p;    p += (size_t)NL * 10;
  float* el1R = p;    p += (size_t)NR * 10;
  float* er1R = p;    p += (size_t)NR * 10;
  float* el2L = p;    p += NL;
  float* er2L = p;    p += NL;
  float* el2R = p;    p += NR;
  float* er2R = p;    p += NR;
  float* wal1l = p;   p += 640;
  float* war1l = p;   p += 640;
  float* wal1r = p;   p += 640;
  float* war1r = p;   p += 640;
  float* wal2l = p;   p += 64;
  float* war2l = p;   p += 64;
  float* wal2r = p;   p += 64;
  float* war2r = p;   p += 64;
  float* zero_base = p;
  float* readout = p; p += 32 * 256;
  int* ip = (int*)p;
  int* degL = ip;     ip += NL;
  int* cntL = ip;     ip += 1;
  int* degR = ip;     ip += NR;
  int* cntR = ip;     ip += 1;
  size_t zero_bytes = (size_t)((char*)ip - (char*)zero_base);
  int* rpL = ip;      ip += NL;
  int* curL = ip;     ip += NL;
  int* srcsL = ip;    ip += EL;
  int* rpR = ip;      ip += NR;
  int* curR = ip;     ip += NR;
  int* srcsR = ip;    ip += ER;

  hipMemsetAsync(zero_base, 0, zero_bytes, stream);

  prep_wal2_kernel<10, 64><<<160, 512, 0, stream>>>(W1l, al1l, ar1l, wal1l, war1l, 80,
                                                    W1r, al1r, ar1r, wal1r, war1r);
  prep_wal2_kernel<1, 128><<<16, 512, 0, stream>>>(W2l, al2l, ar2l, wal2l, war2l, 8,
                                                   W2r, al2r, ar2r, wal2r, war2r);
  deg2_kernel<<<cdiv(EL, 256) + cdiv(ER, 256), 256, 0, stream>>>(
      dst_lig, degL, EL, cdiv(EL, 256), dst_rec, degR, ER);
  rowptr2_kernel<<<cdiv(NL, 256) + cdiv(NR, 256), 256, 0, stream>>>(
      degL, rpL, curL, cntL, NL, cdiv(NL, 256), degR, rpR, curR, cntR, NR);
  elr10_2_kernel<<<cdiv(NL, 4) + cdiv(NR, 4), 256, 0, stream>>>(
      x_lig, wal1l, war1l, el1L, er1L, NL, cdiv(NL, 4),
      x_rec, wal1r, war1r, el1R, er1R, NR);
  scatter_ex2_kernel<<<cdiv(EL, 256) + cdiv(ER, 256), 256, 0, stream>>>(
      src_lig, dst_lig, curL, srcsL, el1L, er1L, ex1L, EL, cdiv(EL, 256),
      src_rec, dst_rec, curR, srcsR, el1R, er1R, ex1R, ER);
  aggr_z10_2_kernel<<<cdiv(NL, 8) + cdiv(NR, 8), 512, 0, stream>>>(
      rpL, degL, srcsL, x_lig, ex1L, zL, NL, cdiv(NL, 8),
      rpR, degR, srcsR, x_rec, ex1R, zR, NR);
  gemm_sumheads2_kernel<<<cdiv(NL, 16) + cdiv(NR, 16), 640, 0, stream>>>(
      zL, W1l, b1l, wal2l, war2l, h1L, el2L, er2L, NL, cdiv(NL, 16),
      zR, W1r, b1r, wal2r, war2r, h1R, el2R, er2R, NR);
  aggr_z1_2_kernel<<<cdiv(NL, 8) + cdiv(NR, 8), 512, 0, stream>>>(
      rpL, degL, srcsL, h1L, el2L, er2L, z2L, NL, cdiv(NL, 8),
      rpR, degR, srcsR, h1R, el2R, er2R, z2R, NR);
  gemm2_readout3_kernel<<<cdiv(NL, 16) + cdiv(NR, 16), 128, 0, stream>>>(
      z2L, W2l, b2l, gid_lig, NL, 0, cdiv(NL, 16),
      z2R, W2r, b2r, gid_rec, NR, 128, readout);

  mlp_kernel<<<32, 128, 0, stream>>>(readout, W_lin1, b_lin1, W_lin2, b_lin2, (float*)d_out);
}

// Round 12
// 480.102 us; speedup vs baseline: 1.3466x; 1.0303x over previous
//
#include <hip/hip_runtime.h>

#define LRELU(x) fmaxf((x), 0.2f*(x))   // identical result to x>0?x:0.2x
#define ZPAD(f) ((f) + 4*((f)>>6))      // 640-float row -> 680 padded (4/head)

static inline int cdiv(int a, int b) { return (a + b - 1) / b; }

// ---------------------------------------------------------------------------
// prep (merged branches): wal[h*64+k] = sum_d W[k, h*DH+d] * al[h*DH+d].
// ---------------------------------------------------------------------------
template<int H, int DH>
__global__ void prep_wal2_kernel(const float* __restrict__ WA, const float* __restrict__ alA,
                                 const float* __restrict__ arA, float* __restrict__ walA,
                                 float* __restrict__ warA, int nbA,
                                 const float* __restrict__ WB, const float* __restrict__ alB,
                                 const float* __restrict__ arB, float* __restrict__ walB,
                                 float* __restrict__ warB) {
  constexpr int K = 64;
  constexpr int HD = H * DH;
  const float *W, *al, *ar; float *wal, *war; int bid;
  if (blockIdx.x < (unsigned)nbA) { W=WA; al=alA; ar=arA; wal=walA; war=warA; bid=blockIdx.x; }
  else { W=WB; al=alB; ar=arB; wal=walB; war=warB; bid=blockIdx.x-nbA; }
  const int wv = threadIdx.x >> 6, lane = threadIdx.x & 63;
  const int o = bid * (blockDim.x >> 6) + wv;
  if (o >= H * K) return;
  const int h = o / K, k = o - h * K;
  float pl = 0.f, pr = 0.f;
#pragma unroll
  for (int j = 0; j < DH / 64; j++) {
    int d = j * 64 + lane;
    float w = W[(size_t)k * HD + h * DH + d];
    pl += w * al[h * DH + d];
    pr += w * ar[h * DH + d];
  }
#pragma unroll
  for (int off = 32; off >= 1; off >>= 1) {
    pl += __shfl_xor(pl, off);
    pr += __shfl_xor(pr, off);
  }
  if (lane == 0) { wal[o] = pl; war[o] = pr; }
}

// ---------------------------------------------------------------------------
// el/er for layer 1 (merged). One wave per node.
// ---------------------------------------------------------------------------
__global__ void elr10_2_kernel(const float* __restrict__ xA, const float* __restrict__ walA,
                               const float* __restrict__ warA, float* __restrict__ elA,
                               float* __restrict__ erA, int NA, int nbA,
                               const float* __restrict__ xB, const float* __restrict__ walB,
                               const float* __restrict__ warB, float* __restrict__ elB,
                               float* __restrict__ erB, int NB) {
  const float *x, *wal, *war; float *el, *er; int N, bid;
  if (blockIdx.x < (unsigned)nbA) { x=xA; wal=walA; war=warA; el=elA; er=erA; N=NA; bid=blockIdx.x; }
  else { x=xB; wal=walB; war=warB; el=elB; er=erB; N=NB; bid=blockIdx.x-nbA; }
  const int wv = threadIdx.x >> 6, lane = threadIdx.x & 63;
  const int n = bid * (blockDim.x >> 6) + wv;
  if (n >= N) return;
  const float xv = x[(size_t)n * 64 + lane];
#pragma unroll
  for (int h = 0; h < 10; h++) {
    float pl = xv * wal[h * 64 + lane];
    float pr = xv * war[h * 64 + lane];
#pragma unroll
    for (int off = 32; off >= 1; off >>= 1) {
      pl += __shfl_xor(pl, off);
      pr += __shfl_xor(pr, off);
    }
    if (lane == 0) { el[(size_t)n * 10 + h] = pl; er[(size_t)n * 10 + h] = pr; }
  }
}

// ---------------------------------------------------------------------------
// CSR build (merged): deg count -> wave-atomic row offsets -> scatter+exp
// ---------------------------------------------------------------------------
__global__ void deg2_kernel(const int* __restrict__ dstA, int* __restrict__ degA, int EA, int nbA,
                            const int* __restrict__ dstB, int* __restrict__ degB, int EB) {
  const int* dst; int* deg; int E, t;
  if (blockIdx.x < (unsigned)nbA) { dst=dstA; deg=degA; E=EA; t=blockIdx.x*256+threadIdx.x; }
  else { dst=dstB; deg=degB; E=EB; t=(blockIdx.x-nbA)*256+threadIdx.x; }
  if (t < E) atomicAdd(&deg[dst[t]], 1);
}

__global__ void rowptr2_kernel(const int* __restrict__ degA, int* __restrict__ rpA,
                               int* __restrict__ curA, int* __restrict__ cntA, int NA, int nbA,
                               const int* __restrict__ degB, int* __restrict__ rpB,
                               int* __restrict__ curB, int* __restrict__ cntB, int NB) {
  const int* deg; int *rp, *cur, *cnt; int N, t;
  if (blockIdx.x < (unsigned)nbA) { deg=degA; rp=rpA; cur=curA; cnt=cntA; N=NA; t=blockIdx.x*256+threadIdx.x; }
  else { deg=degB; rp=rpB; cur=curB; cnt=cntB; N=NB; t=(blockIdx.x-nbA)*256+threadIdx.x; }
  int lane = threadIdx.x & 63;
  int v = (t < N) ? deg[t] : 0;
  int x = v;
#pragma unroll
  for (int off = 1; off < 64; off <<= 1) {
    int y = __shfl_up(x, off);
    if (lane >= off) x += y;
  }
  int total = __shfl(x, 63);
  int base = 0;
  if (lane == 0 && total > 0) base = atomicAdd(cnt, total);
  base = __shfl(base, 0);
  int excl = base + x - v;
  if (t < N) { rp[t] = excl; cur[t] = excl; }
}

// scatter + per-edge layer-1 exp + record slot for the layer-2 ex pass
__global__ void scatter_ex2_kernel(
    const int* __restrict__ srcA, const int* __restrict__ dstA, int* __restrict__ curA,
    int* __restrict__ outA, const float* __restrict__ elA, const float* __restrict__ erA,
    float* __restrict__ exA, int* __restrict__ eslotA, int EA, int nbA,
    const int* __restrict__ srcB, const int* __restrict__ dstB, int* __restrict__ curB,
    int* __restrict__ outB, const float* __restrict__ elB, const float* __restrict__ erB,
    float* __restrict__ exB, int* __restrict__ eslotB, int EB) {
  const int *src, *dst; int *cur, *out, *eslot; const float *el, *er; float *ex; int E, t;
  if (blockIdx.x < (unsigned)nbA) { src=srcA; dst=dstA; cur=curA; out=outA; el=elA; er=erA; ex=exA; eslot=eslotA; E=EA; t=blockIdx.x*256+threadIdx.x; }
  else { src=srcB; dst=dstB; cur=curB; out=outB; el=elB; er=erB; ex=exB; eslot=eslotB; E=EB; t=(blockIdx.x-nbA)*256+threadIdx.x; }
  if (t >= E) return;
  const int s = src[t], d = dst[t];
  const int slot = atomicAdd(&cur[d], 1);
  out[slot] = s;
  eslot[t] = slot;
  const float2* elv = (const float2*)el;
  const float2* erv = (const float2*)er;
  float2* exv = (float2*)ex;
#pragma unroll
  for (int j = 0; j < 5; j++) {
    float2 a = elv[(size_t)s * 5 + j];
    float2 b = erv[(size_t)d * 5 + j];
    float2 e;
    e.x = __expf(LRELU(a.x + b.x));
    e.y = __expf(LRELU(a.y + b.y));
    exv[(size_t)slot * 5 + j] = e;
  }
}

// layer-2 per-edge exp (edge-parallel, after el2/er2 exist)
__global__ void ex2_2_kernel(const int* __restrict__ srcA, const int* __restrict__ dstA,
                             const int* __restrict__ eslotA, const float* __restrict__ el2A,
                             const float* __restrict__ er2A, float* __restrict__ ex2A,
                             int EA, int nbA,
                             const int* __restrict__ srcB, const int* __restrict__ dstB,
                             const int* __restrict__ eslotB, const float* __restrict__ el2B,
                             const float* __restrict__ er2B, float* __restrict__ ex2B, int EB) {
  const int *src, *dst, *eslot; const float *el2, *er2; float *ex2; int E, t;
  if (blockIdx.x < (unsigned)nbA) { src=srcA; dst=dstA; eslot=eslotA; el2=el2A; er2=er2A; ex2=ex2A; E=EA; t=blockIdx.x*256+threadIdx.x; }
  else { src=srcB; dst=dstB; eslot=eslotB; el2=el2B; er2=er2B; ex2=ex2B; E=EB; t=(blockIdx.x-nbA)*256+threadIdx.x; }
  if (t >= E) return;
  ex2[eslot[t]] = __expf(LRELU(el2[src[t]] + er2[dst[t]]));
}

// ---------------------------------------------------------------------------
// Layer-1 aggregation (merged): one wave per node, 10 heads in registers.
// ---------------------------------------------------------------------------
__global__ void aggr_z10_2_kernel(const int* __restrict__ rpA, const int* __restrict__ degA,
                                  const int* __restrict__ srcsA, const float* __restrict__ xA,
                                  const float* __restrict__ exA, float* __restrict__ zA,
                                  int NA, int nbA,
                                  const int* __restrict__ rpB, const int* __restrict__ degB,
                                  const int* __restrict__ srcsB, const float* __restrict__ xB,
                                  const float* __restrict__ exB, float* __restrict__ zB, int NB) {
  const int *rp, *degp, *srcs; const float *x, *ex; float *z; int N, bid;
  if (blockIdx.x < (unsigned)nbA) { rp=rpA; degp=degA; srcs=srcsA; x=xA; ex=exA; z=zA; N=NA; bid=blockIdx.x; }
  else { rp=rpB; degp=degB; srcs=srcsB; x=xB; ex=exB; z=zB; N=NB; bid=blockIdx.x-nbA; }
  const int wv = threadIdx.x >> 6, lane = threadIdx.x & 63;
  const int n = bid * (blockDim.x >> 6) + wv;
  if (n >= N) return;
  const int beg = rp[n], dg = degp[n];
  const float2* exv = (const float2*)ex;
  float den[10], acc[10];
#pragma unroll
  for (int h = 0; h < 10; h++) { den[h] = 0.f; acc[h] = 0.f; }
  int i = 0;
  for (; i + 1 < dg; i += 2) {
    int s0 = srcs[beg + i], s1 = srcs[beg + i + 1];
    float xv0 = x[(size_t)s0 * 64 + lane];
    float xv1 = x[(size_t)s1 * 64 + lane];
    float e0[10], e1[10];
#pragma unroll
    for (int j = 0; j < 5; j++) {
      float2 a = exv[(size_t)(beg + i) * 5 + j];
      float2 c = exv[(size_t)(beg + i + 1) * 5 + j];
      e0[2 * j] = a.x; e0[2 * j + 1] = a.y;
      e1[2 * j] = c.x; e1[2 * j + 1] = c.y;
    }
#pragma unroll
    for (int h = 0; h < 10; h++) {
      den[h] += e0[h] + e1[h];
      acc[h] = fmaf(e0[h], xv0, fmaf(e1[h], xv1, acc[h]));
    }
  }
  if (i < dg) {
    int s0 = srcs[beg + i];
    float xv0 = x[(size_t)s0 * 64 + lane];
#pragma unroll
    for (int j = 0; j < 5; j++) {
      float2 a = exv[(size_t)(beg + i) * 5 + j];
      den[2 * j] += a.x;
      den[2 * j + 1] += a.y;
      acc[2 * j] = fmaf(a.x, xv0, acc[2 * j]);
      acc[2 * j + 1] = fmaf(a.y, xv0, acc[2 * j + 1]);
    }
  }
#pragma unroll
  for (int h = 0; h < 10; h++)
    z[(size_t)n * 640 + h * 64 + lane] = (dg > 0) ? acc[h] / den[h] : 0.f;
}

// ---------------------------------------------------------------------------
// Layer-2 aggregation (merged, H=1): one wave per node, precomputed ex2.
// Per edge: 1 srcs load + 1 ex load + 1 h-row load + 1 add + 1 FMA.
// ---------------------------------------------------------------------------
__global__ void aggr_z1_2_kernel(const int* __restrict__ rpA, const int* __restrict__ degA,
                                 const int* __restrict__ srcsA, const float* __restrict__ hA,
                                 const float* __restrict__ exA, float* __restrict__ zA,
                                 int NA, int nbA,
                                 const int* __restrict__ rpB, const int* __restrict__ degB,
                                 const int* __restrict__ srcsB, const float* __restrict__ hB,
                                 const float* __restrict__ exB, float* __restrict__ zB, int NB) {
  const int *rp, *degp, *srcs; const float *hin, *ex; float *z; int N, bid;
  if (blockIdx.x < (unsigned)nbA) { rp=rpA; degp=degA; srcs=srcsA; hin=hA; ex=exA; z=zA; N=NA; bid=blockIdx.x; }
  else { rp=rpB; degp=degB; srcs=srcsB; hin=hB; ex=exB; z=zB; N=NB; bid=blockIdx.x-nbA; }
  const int wv = threadIdx.x >> 6, lane = threadIdx.x & 63;
  const int n = bid * (blockDim.x >> 6) + wv;
  if (n >= N) return;
  const int beg = rp[n], dg = degp[n];
  float den = 0.f, acc = 0.f;
  int i = 0;
  for (; i + 1 < dg; i += 2) {
    int s0 = srcs[beg + i], s1 = srcs[beg + i + 1];
    float e0 = ex[beg + i], e1 = ex[beg + i + 1];
    den += e0 + e1;
    acc = fmaf(e0, hin[(size_t)s0 * 64 + lane], fmaf(e1, hin[(size_t)s1 * 64 + lane], acc));
  }
  if (i < dg) {
    int s0 = srcs[beg + i];
    float e0 = ex[beg + i];
    den += e0;
    acc = fmaf(e0, hin[(size_t)s0 * 64 + lane], acc);
  }
  z[(size_t)n * 64 + lane] = (dg > 0) ? acc / den : 0.f;
}

// ---------------------------------------------------------------------------
// Layer-1 GEMM + relu + head-sum + fused el2/er2, W double-buffered so the
// L2 W-loads overlap the 64-FMA burst (VGPR target <= 64 to keep 3 blk/CU).
// ---------------------------------------------------------------------------
__global__ void gemm_sumheads2_kernel(
    const float* __restrict__ zA, const float* __restrict__ WA, const float* __restrict__ bA,
    const float* __restrict__ wal2A, const float* __restrict__ war2A, float* __restrict__ h1A,
    float* __restrict__ el2A, float* __restrict__ er2A, int NA, int nbA,
    const float* __restrict__ zB, const float* __restrict__ WB, const float* __restrict__ bB,
    const float* __restrict__ wal2B, const float* __restrict__ war2B, float* __restrict__ h1B,
    float* __restrict__ el2B, float* __restrict__ er2B, int NB) {
  constexpr int NPB = 16;
  __shared__ float zs[NPB][680];
  const float *z, *W, *bb, *wal2, *war2; float *h1sum, *el2, *er2; int N, tile;
  if (blockIdx.x < (unsigned)nbA) { z=zA; W=WA; bb=bA; wal2=wal2A; war2=war2A; h1sum=h1A; el2=el2A; er2=er2A; N=NA; tile=blockIdx.x; }
  else { z=zB; W=WB; bb=bB; wal2=wal2B; war2=war2B; h1sum=h1B; el2=el2B; er2=er2B; N=NB; tile=blockIdx.x-nbA; }
  const int f = threadIdx.x;      // 640
  const int n0 = tile * NPB;
  const int pf = ZPAD(f);
#pragma unroll
  for (int i = 0; i < NPB; i++) {
    int n = n0 + i;
    zs[i][pf] = (n < N) ? z[(size_t)n * 640 + f] : 0.f;
  }
  __syncthreads();
  const int f4 = f % 160;         // outputs 4*f4 .. 4*f4+3
  const int ng = f / 160;         // node group: nodes ng*4 .. ng*4+3
  const int head = f4 >> 4;
  const int base = 68 * head;     // padded offset of k=0 within this head
  float acc[4][4];
#pragma unroll
  for (int i = 0; i < 4; i++)
#pragma unroll
    for (int j = 0; j < 4; j++) acc[i][j] = 0.f;
  const float4* W4 = (const float4*)W;
  float4 wn[4];
#pragma unroll
  for (int j = 0; j < 4; j++) wn[j] = W4[(size_t)j * 160 + f4];
#pragma unroll
  for (int k4 = 0; k4 < 16; k4++) {
    float4 wc[4];
#pragma unroll
    for (int j = 0; j < 4; j++) wc[j] = wn[j];
    if (k4 < 15) {
#pragma unroll
      for (int j = 0; j < 4; j++) wn[j] = W4[(size_t)(4 * (k4 + 1) + j) * 160 + f4];
    }
    float4 zq[4];
#pragma unroll
    for (int i = 0; i < 4; i++)
      zq[i] = *(const float4*)&zs[ng * 4 + i][base + 4 * k4];
#pragma unroll
    for (int j4 = 0; j4 < 4; j4++) {
      const float4 w4 = wc[j4];
#pragma unroll
      for (int i = 0; i < 4; i++) {
        const float zv = j4 == 0 ? zq[i].x : j4 == 1 ? zq[i].y : j4 == 2 ? zq[i].z : zq[i].w;
        acc[i][0] = fmaf(zv, w4.x, acc[i][0]);
        acc[i][1] = fmaf(zv, w4.y, acc[i][1]);
        acc[i][2] = fmaf(zv, w4.z, acc[i][2]);
        acc[i][3] = fmaf(zv, w4.w, acc[i][3]);
      }
    }
  }
  const float4 b4 = ((const float4*)bb)[f4];
  __syncthreads();
#pragma unroll
  for (int i = 0; i < 4; i++) {
    float* row = &zs[ng * 4 + i][ZPAD(4 * f4)];   // 4 consecutive (same head)
    row[0] = fmaxf(acc[i][0] + b4.x, 0.f);
    row[1] = fmaxf(acc[i][1] + b4.y, 0.f);
    row[2] = fmaxf(acc[i][2] + b4.z, 0.f);
    row[3] = fmaxf(acc[i][3] + b4.w, 0.f);
  }
  __syncthreads();
  const int lane = threadIdx.x & 63;
  for (int idx = threadIdx.x; idx < NPB * 64; idx += 640) {
    const int i = idx >> 6, d = idx & 63;
    float s = 0.f;
#pragma unroll
    for (int h = 0; h < 10; h++) s += zs[i][68 * h + d];
    const int n = n0 + i;
    float pl = s * wal2[d], pr = s * war2[d];
#pragma unroll
    for (int off = 32; off >= 1; off >>= 1) {
      pl += __shfl_xor(pl, off);
      pr += __shfl_xor(pr, off);
    }
    if (n < N) {
      h1sum[(size_t)n * 64 + d] = s;
      if (lane == 0) { el2[n] = pl; er2[n] = pr; }
    }
  }
}

// ---------------------------------------------------------------------------
// Layer-2 GEMM + relu + block-local segment-max, one atomic per gid-run/col.
// ---------------------------------------------------------------------------
__global__ void gemm2_readout3_kernel(
    const float* __restrict__ zA, const float* __restrict__ WA, const float* __restrict__ bA,
    const int* __restrict__ gidA, int NA, int coA, int nbA,
    const float* __restrict__ zB, const float* __restrict__ WB, const float* __restrict__ bB,
    const int* __restrict__ gidB, int NB, int coB,
    float* __restrict__ readout) {
  constexpr int NPB = 16;
  __shared__ float zs[NPB][64];
  __shared__ float vals[NPB][128];
  __shared__ int gids[NPB];
  const float *z, *W, *bb; const int* gid; int N, colOff, tile;
  if (blockIdx.x < (unsigned)nbA) { z=zA; W=WA; bb=bA; gid=gidA; N=NA; colOff=coA; tile=blockIdx.x; }
  else { z=zB; W=WB; bb=bB; gid=gidB; N=NB; colOff=coB; tile=blockIdx.x-nbA; }
  const int f = threadIdx.x;      // 128
  const int n0 = tile * NPB;
  for (int idx = f; idx < NPB * 64; idx += 128) {
    int i = idx >> 6, k = idx & 63;
    int n = n0 + i;
    zs[i][k] = (n < N) ? z[(size_t)n * 64 + k] : 0.f;
  }
  if (f < NPB) gids[f] = (n0 + f < N) ? gid[n0 + f] : -1;
  __syncthreads();
  float acc[NPB];
#pragma unroll
  for (int i = 0; i < NPB; i++) acc[i] = 0.f;
#pragma unroll 4
  for (int k4 = 0; k4 < 16; k4++) {
    const float w0 = W[(size_t)(4 * k4 + 0) * 128 + f];
    const float w1 = W[(size_t)(4 * k4 + 1) * 128 + f];
    const float w2 = W[(size_t)(4 * k4 + 2) * 128 + f];
    const float w3 = W[(size_t)(4 * k4 + 3) * 128 + f];
#pragma unroll
    for (int i = 0; i < NPB; i++) {
      float4 zq = *(const float4*)&zs[i][4 * k4];
      acc[i] = fmaf(zq.x, w0, fmaf(zq.y, w1, fmaf(zq.z, w2, fmaf(zq.w, w3, acc[i]))));
    }
  }
  const float bbf = bb[f];
#pragma unroll
  for (int i = 0; i < NPB; i++) vals[i][f] = fmaxf(acc[i] + bbf, 0.f);
  __syncthreads();
  float run = 0.f;
  int curg = -1;
#pragma unroll
  for (int i = 0; i < NPB; i++) {
    int g = gids[i];
    if (g < 0) break;
    if (g != curg) {
      if (curg >= 0)
        atomicMax((unsigned int*)&readout[curg * 256 + colOff + f], __float_as_uint(run));
      curg = g;
      run = 0.f;
    }
    run = fmaxf(run, vals[i][f]);
  }
  if (curg >= 0)
    atomicMax((unsigned int*)&readout[curg * 256 + colOff + f], __float_as_uint(run));
}

// MLP: relu(concat @ W1 + b1) @ W2 + b2 -> relu -> out[32]
__global__ void mlp_kernel(const float* __restrict__ readout, const float* __restrict__ W1,
                           const float* __restrict__ b1, const float* __restrict__ W2,
                           const float* __restrict__ b2, float* __restrict__ out) {
  int b = blockIdx.x;   // 32
  int j = threadIdx.x;  // 128
  __shared__ float rs[256];
  rs[j] = readout[b * 256 + j];
  rs[j + 128] = readout[b * 256 + 128 + j];
  __syncthreads();
  float acc = b1[j];
#pragma unroll 8
  for (int k = 0; k < 256; k++) acc += rs[k] * W1[k * 128 + j];
  acc = fmaxf(acc, 0.f);
  float p = acc * W2[j];
#pragma unroll
  for (int off = 32; off >= 1; off >>= 1) p += __shfl_xor(p, off);
  __shared__ float wsum[2];
  if ((threadIdx.x & 63) == 0) wsum[threadIdx.x >> 6] = p;
  __syncthreads();
  if (threadIdx.x == 0) {
    float s = wsum[0] + wsum[1] + b2[0];
    out[b] = fmaxf(s, 0.f);
  }
}

// ---------------------------------------------------------------------------
extern "C" void kernel_launch(void* const* d_in, const int* in_sizes, int n_in,
                              void* d_out, int out_size, void* d_ws, size_t ws_size,
                              hipStream_t stream) {
  const float* x_lig = (const float*)d_in[0];
  const int* src_lig = (const int*)d_in[1];
  const int* dst_lig = (const int*)d_in[2];
  const int* gid_lig = (const int*)d_in[3];
  const float* x_rec = (const float*)d_in[4];
  const int* src_rec = (const int*)d_in[5];
  const int* dst_rec = (const int*)d_in[6];
  const int* gid_rec = (const int*)d_in[7];
  const float* W1l = (const float*)d_in[8];
  const float* al1l = (const float*)d_in[9];
  const float* ar1l = (const float*)d_in[10];
  const float* b1l = (const float*)d_in[11];
  const float* W2l = (const float*)d_in[12];
  const float* al2l = (const float*)d_in[13];
  const float* ar2l = (const float*)d_in[14];
  const float* b2l = (const float*)d_in[15];
  const float* W1r = (const float*)d_in[16];
  const float* al1r = (const float*)d_in[17];
  const float* ar1r = (const float*)d_in[18];
  const float* b1r = (const float*)d_in[19];
  const float* W2r = (const float*)d_in[20];
  const float* al2r = (const float*)d_in[21];
  const float* ar2r = (const float*)d_in[22];
  const float* b2r = (const float*)d_in[23];
  const float* W_lin1 = (const float*)d_in[24];
  const float* b_lin1 = (const float*)d_in[25];
  const float* W_lin2 = (const float*)d_in[26];
  const float* b_lin2 = (const float*)d_in[27];

  const int NL = 10000, EL = 80000, NR = 30000, ER = 480000;
  float* p = (float*)d_ws;
  float* zL = p;      p += (size_t)NL * 640;
  float* zR = p;      p += (size_t)NR * 640;
  float* ex1L = p;    p += (size_t)EL * 10;
  float* ex1R = p;    p += (size_t)ER * 10;
  float* ex2L = p;    p += EL;
  float* ex2R = p;    p += ER;
  float* z2L = p;     p += (size_t)NL * 64;
  float* z2R = p;     p += (size_t)NR * 64;
  float* h1L = p;     p += (size_t)NL * 64;
  float* h1R = p;     p += (size_t)NR * 64;
  float* el1L = p;    p += (size_t)NL * 10;
  float* er1L = p;    p += (size_t)NL * 10;
  float* el1R = p;    p += (size_t)NR * 10;
  float* er1R = p;    p += (size_t)NR * 10;
  float* el2L = p;    p += NL;
  float* er2L = p;    p += NL;
  float* el2R = p;    p += NR;
  float* er2R = p;    p += NR;
  float* wal1l = p;   p += 640;
  float* war1l = p;   p += 640;
  float* wal1r = p;   p += 640;
  float* war1r = p;   p += 640;
  float* wal2l = p;   p += 64;
  float* war2l = p;   p += 64;
  float* wal2r = p;   p += 64;
  float* war2r = p;   p += 64;
  float* zero_base = p;
  float* readout = p; p += 32 * 256;
  int* ip = (int*)p;
  int* degL = ip;     ip += NL;
  int* cntL = ip;     ip += 1;
  int* degR = ip;     ip += NR;
  int* cntR = ip;     ip += 1;
  size_t zero_bytes = (size_t)((char*)ip - (char*)zero_base);
  int* rpL = ip;      ip += NL;
  int* curL = ip;     ip += NL;
  int* srcsL = ip;    ip += EL;
  int* rpR = ip;      ip += NR;
  int* curR = ip;     ip += NR;
  int* srcsR = ip;    ip += ER;
  int* eslotL = ip;   ip += EL;
  int* eslotR = ip;   ip += ER;

  hipMemsetAsync(zero_base, 0, zero_bytes, stream);

  prep_wal2_kernel<10, 64><<<160, 512, 0, stream>>>(W1l, al1l, ar1l, wal1l, war1l, 80,
                                                    W1r, al1r, ar1r, wal1r, war1r);
  prep_wal2_kernel<1, 128><<<16, 512, 0, stream>>>(W2l, al2l, ar2l, wal2l, war2l, 8,
                                                   W2r, al2r, ar2r, wal2r, war2r);
  deg2_kernel<<<cdiv(EL, 256) + cdiv(ER, 256), 256, 0, stream>>>(
      dst_lig, degL, EL, cdiv(EL, 256), dst_rec, degR, ER);
  rowptr2_kernel<<<cdiv(NL, 256) + cdiv(NR, 256), 256, 0, stream>>>(
      degL, rpL, curL, cntL, NL, cdiv(NL, 256), degR, rpR, curR, cntR, NR);
  elr10_2_kernel<<<cdiv(NL, 4) + cdiv(NR, 4), 256, 0, stream>>>(
      x_lig, wal1l, war1l, el1L, er1L, NL, cdiv(NL, 4),
      x_rec, wal1r, war1r, el1R, er1R, NR);
  scatter_ex2_kernel<<<cdiv(EL, 256) + cdiv(ER, 256), 256, 0, stream>>>(
      src_lig, dst_lig, curL, srcsL, el1L, er1L, ex1L, eslotL, EL, cdiv(EL, 256),
      src_rec, dst_rec, curR, srcsR, el1R, er1R, ex1R, eslotR, ER);
  aggr_z10_2_kernel<<<cdiv(NL, 8) + cdiv(NR, 8), 512, 0, stream>>>(
      rpL, degL, srcsL, x_lig, ex1L, zL, NL, cdiv(NL, 8),
      rpR, degR, srcsR, x_rec, ex1R, zR, NR);
  gemm_sumheads2_kernel<<<cdiv(NL, 16) + cdiv(NR, 16), 640, 0, stream>>>(
      zL, W1l, b1l, wal2l, war2l, h1L, el2L, er2L, NL, cdiv(NL, 16),
      zR, W1r, b1r, wal2r, war2r, h1R, el2R, er2R, NR);
  ex2_2_kernel<<<cdiv(EL, 256) + cdiv(ER, 256), 256, 0, stream>>>(
      src_lig, dst_lig, eslotL, el2L, er2L, ex2L, EL, cdiv(EL, 256),
      src_rec, dst_rec, eslotR, el2R, er2R, ex2R, ER);
  aggr_z1_2_kernel<<<cdiv(NL, 8) + cdiv(NR, 8), 512, 0, stream>>>(
      rpL, degL, srcsL, h1L, ex2L, z2L, NL, cdiv(NL, 8),
      rpR, degR, srcsR, h1R, ex2R, z2R, NR);
  gemm2_readout3_kernel<<<cdiv(NL, 16) + cdiv(NR, 16), 128, 0, stream>>>(
      z2L, W2l, b2l, gid_lig, NL, 0, cdiv(NL, 16),
      z2R, W2r, b2r, gid_rec, NR, 128, readout);

  mlp_kernel<<<32, 128, 0, stream>>>(readout, W_lin1, b_lin1, W_lin2, b_lin2, (float*)d_out);
}

// Round 14
// 475.946 us; speedup vs baseline: 1.3584x; 1.0087x over previous
//
#include <hip/hip_runtime.h>

#define LRELU(x) fmaxf((x), 0.2f*(x))   // identical result to x>0?x:0.2x
#define ZPAD(f) ((f) + 4*((f)>>6))      // 640-float row -> 680 padded (4/head)

static inline int cdiv(int a, int b) { return (a + b - 1) / b; }

// ---------------------------------------------------------------------------
// prep (merged branches): wal[h*64+k] = sum_d W[k, h*DH+d] * al[h*DH+d].
// ---------------------------------------------------------------------------
template<int H, int DH>
__global__ void prep_wal2_kernel(const float* __restrict__ WA, const float* __restrict__ alA,
                                 const float* __restrict__ arA, float* __restrict__ walA,
                                 float* __restrict__ warA, int nbA,
                                 const float* __restrict__ WB, const float* __restrict__ alB,
                                 const float* __restrict__ arB, float* __restrict__ walB,
                                 float* __restrict__ warB) {
  constexpr int K = 64;
  constexpr int HD = H * DH;
  const float *W, *al, *ar; float *wal, *war; int bid;
  if (blockIdx.x < (unsigned)nbA) { W=WA; al=alA; ar=arA; wal=walA; war=warA; bid=blockIdx.x; }
  else { W=WB; al=alB; ar=arB; wal=walB; war=warB; bid=blockIdx.x-nbA; }
  const int wv = threadIdx.x >> 6, lane = threadIdx.x & 63;
  const int o = bid * (blockDim.x >> 6) + wv;
  if (o >= H * K) return;
  const int h = o / K, k = o - h * K;
  float pl = 0.f, pr = 0.f;
#pragma unroll
  for (int j = 0; j < DH / 64; j++) {
    int d = j * 64 + lane;
    float w = W[(size_t)k * HD + h * DH + d];
    pl += w * al[h * DH + d];
    pr += w * ar[h * DH + d];
  }
#pragma unroll
  for (int off = 32; off >= 1; off >>= 1) {
    pl += __shfl_xor(pl, off);
    pr += __shfl_xor(pr, off);
  }
  if (lane == 0) { wal[o] = pl; war[o] = pr; }
}

// ---------------------------------------------------------------------------
// el/er for layer 1 (merged). One wave per node.
// ---------------------------------------------------------------------------
__global__ void elr10_2_kernel(const float* __restrict__ xA, const float* __restrict__ walA,
                               const float* __restrict__ warA, float* __restrict__ elA,
                               float* __restrict__ erA, int NA, int nbA,
                               const float* __restrict__ xB, const float* __restrict__ walB,
                               const float* __restrict__ warB, float* __restrict__ elB,
                               float* __restrict__ erB, int NB) {
  const float *x, *wal, *war; float *el, *er; int N, bid;
  if (blockIdx.x < (unsigned)nbA) { x=xA; wal=walA; war=warA; el=elA; er=erA; N=NA; bid=blockIdx.x; }
  else { x=xB; wal=walB; war=warB; el=elB; er=erB; N=NB; bid=blockIdx.x-nbA; }
  const int wv = threadIdx.x >> 6, lane = threadIdx.x & 63;
  const int n = bid * (blockDim.x >> 6) + wv;
  if (n >= N) return;
  const float xv = x[(size_t)n * 64 + lane];
#pragma unroll
  for (int h = 0; h < 10; h++) {
    float pl = xv * wal[h * 64 + lane];
    float pr = xv * war[h * 64 + lane];
#pragma unroll
    for (int off = 32; off >= 1; off >>= 1) {
      pl += __shfl_xor(pl, off);
      pr += __shfl_xor(pr, off);
    }
    if (lane == 0) { el[(size_t)n * 10 + h] = pl; er[(size_t)n * 10 + h] = pr; }
  }
}

// ---------------------------------------------------------------------------
// CSR build (merged): deg count -> wave-atomic row offsets -> scatter+exp
// ---------------------------------------------------------------------------
__global__ void deg2_kernel(const int* __restrict__ dstA, int* __restrict__ degA, int EA, int nbA,
                            const int* __restrict__ dstB, int* __restrict__ degB, int EB) {
  const int* dst; int* deg; int E, t;
  if (blockIdx.x < (unsigned)nbA) { dst=dstA; deg=degA; E=EA; t=blockIdx.x*256+threadIdx.x; }
  else { dst=dstB; deg=degB; E=EB; t=(blockIdx.x-nbA)*256+threadIdx.x; }
  if (t < E) atomicAdd(&deg[dst[t]], 1);
}

__global__ void rowptr2_kernel(const int* __restrict__ degA, int* __restrict__ rpA,
                               int* __restrict__ curA, int* __restrict__ cntA, int NA, int nbA,
                               const int* __restrict__ degB, int* __restrict__ rpB,
                               int* __restrict__ curB, int* __restrict__ cntB, int NB) {
  const int* deg; int *rp, *cur, *cnt; int N, t;
  if (blockIdx.x < (unsigned)nbA) { deg=degA; rp=rpA; cur=curA; cnt=cntA; N=NA; t=blockIdx.x*256+threadIdx.x; }
  else { deg=degB; rp=rpB; cur=curB; cnt=cntB; N=NB; t=(blockIdx.x-nbA)*256+threadIdx.x; }
  int lane = threadIdx.x & 63;
  int v = (t < N) ? deg[t] : 0;
  int x = v;
#pragma unroll
  for (int off = 1; off < 64; off <<= 1) {
    int y = __shfl_up(x, off);
    if (lane >= off) x += y;
  }
  int total = __shfl(x, 63);
  int base = 0;
  if (lane == 0 && total > 0) base = atomicAdd(cnt, total);
  base = __shfl(base, 0);
  int excl = base + x - v;
  if (t < N) { rp[t] = excl; cur[t] = excl; }
}

// scatter + per-edge layer-1 exp + record slot for the layer-2 ex pass
__global__ void scatter_ex2_kernel(
    const int* __restrict__ srcA, const int* __restrict__ dstA, int* __restrict__ curA,
    int* __restrict__ outA, const float* __restrict__ elA, const float* __restrict__ erA,
    float* __restrict__ exA, int* __restrict__ eslotA, int EA, int nbA,
    const int* __restrict__ srcB, const int* __restrict__ dstB, int* __restrict__ curB,
    int* __restrict__ outB, const float* __restrict__ elB, const float* __restrict__ erB,
    float* __restrict__ exB, int* __restrict__ eslotB, int EB) {
  const int *src, *dst; int *cur, *out, *eslot; const float *el, *er; float *ex; int E, t;
  if (blockIdx.x < (unsigned)nbA) { src=srcA; dst=dstA; cur=curA; out=outA; el=elA; er=erA; ex=exA; eslot=eslotA; E=EA; t=blockIdx.x*256+threadIdx.x; }
  else { src=srcB; dst=dstB; cur=curB; out=outB; el=elB; er=erB; ex=exB; eslot=eslotB; E=EB; t=(blockIdx.x-nbA)*256+threadIdx.x; }
  if (t >= E) return;
  const int s = src[t], d = dst[t];
  const int slot = atomicAdd(&cur[d], 1);
  out[slot] = s;
  eslot[t] = slot;
  const float2* elv = (const float2*)el;
  const float2* erv = (const float2*)er;
  float2* exv = (float2*)ex;
#pragma unroll
  for (int j = 0; j < 5; j++) {
    float2 a = elv[(size_t)s * 5 + j];
    float2 b = erv[(size_t)d * 5 + j];
    float2 e;
    e.x = __expf(LRELU(a.x + b.x));
    e.y = __expf(LRELU(a.y + b.y));
    exv[(size_t)slot * 5 + j] = e;
  }
}

// layer-2 per-edge exp (edge-parallel, after el2/er2 exist)
__global__ void ex2_2_kernel(const int* __restrict__ srcA, const int* __restrict__ dstA,
                             const int* __restrict__ eslotA, const float* __restrict__ el2A,
                             const float* __restrict__ er2A, float* __restrict__ ex2A,
                             int EA, int nbA,
                             const int* __restrict__ srcB, const int* __restrict__ dstB,
                             const int* __restrict__ eslotB, const float* __restrict__ el2B,
                             const float* __restrict__ er2B, float* __restrict__ ex2B, int EB) {
  const int *src, *dst, *eslot; const float *el2, *er2; float *ex2; int E, t;
  if (blockIdx.x < (unsigned)nbA) { src=srcA; dst=dstA; eslot=eslotA; el2=el2A; er2=er2A; ex2=ex2A; E=EA; t=blockIdx.x*256+threadIdx.x; }
  else { src=srcB; dst=dstB; eslot=eslotB; el2=el2B; er2=er2B; ex2=ex2B; E=EB; t=(blockIdx.x-nbA)*256+threadIdx.x; }
  if (t >= E) return;
  ex2[eslot[t]] = __expf(LRELU(el2[src[t]] + er2[dst[t]]));
}

// ---------------------------------------------------------------------------
// FUSED layer 1: aggregation (10 heads/regs, one wave per node) -> LDS z tile
// -> register-tiled GEMM + relu + head-sum + el2/er2. No global z traffic.
// 640 threads, 16 nodes/block.
// ---------------------------------------------------------------------------
__global__ void aggr_gemm1_kernel(
    const int* __restrict__ rpA, const int* __restrict__ degA, const int* __restrict__ srcsA,
    const float* __restrict__ xA, const float* __restrict__ exA,
    const float* __restrict__ WA, const float* __restrict__ bA,
    const float* __restrict__ wal2A, const float* __restrict__ war2A,
    float* __restrict__ h1A, float* __restrict__ el2A, float* __restrict__ er2A, int NA, int nbA,
    const int* __restrict__ rpB, const int* __restrict__ degB, const int* __restrict__ srcsB,
    const float* __restrict__ xB, const float* __restrict__ exB,
    const float* __restrict__ WB, const float* __restrict__ bB,
    const float* __restrict__ wal2B, const float* __restrict__ war2B,
    float* __restrict__ h1B, float* __restrict__ el2B, float* __restrict__ er2B, int NB) {
  constexpr int NPB = 16;
  __shared__ float zs[NPB][680];
  const int *rp, *degp, *srcs; const float *x, *ex, *W, *bb, *wal2, *war2;
  float *h1sum, *el2, *er2; int N, tile;
  if (blockIdx.x < (unsigned)nbA) {
    rp=rpA; degp=degA; srcs=srcsA; x=xA; ex=exA; W=WA; bb=bA; wal2=wal2A; war2=war2A;
    h1sum=h1A; el2=el2A; er2=er2A; N=NA; tile=blockIdx.x;
  } else {
    rp=rpB; degp=degB; srcs=srcsB; x=xB; ex=exB; W=WB; bb=bB; wal2=wal2B; war2=war2B;
    h1sum=h1B; el2=el2B; er2=er2B; N=NB; tile=blockIdx.x-nbA;
  }
  const int f = threadIdx.x;      // 640
  const int wv = f >> 6, lane = f & 63;
  const int n0 = tile * NPB;
  const float2* exv = (const float2*)ex;
  // ---- phase 1: per-node aggregation straight into LDS ----
  for (int ni = wv; ni < NPB; ni += 10) {
    const int n = n0 + ni;
    float den[10], acc[10];
#pragma unroll
    for (int h = 0; h < 10; h++) { den[h] = 0.f; acc[h] = 0.f; }
    int dg = 0;
    if (n < N) {
      const int beg = rp[n];
      dg = degp[n];
      int i = 0;
      for (; i + 1 < dg; i += 2) {
        int s0 = srcs[beg + i], s1 = srcs[beg + i + 1];
        float xv0 = x[(size_t)s0 * 64 + lane];
        float xv1 = x[(size_t)s1 * 64 + lane];
        float e0[10], e1[10];
#pragma unroll
        for (int j = 0; j < 5; j++) {
          float2 a = exv[(size_t)(beg + i) * 5 + j];
          float2 c = exv[(size_t)(beg + i + 1) * 5 + j];
          e0[2 * j] = a.x; e0[2 * j + 1] = a.y;
          e1[2 * j] = c.x; e1[2 * j + 1] = c.y;
        }
#pragma unroll
        for (int h = 0; h < 10; h++) {
          den[h] += e0[h] + e1[h];
          acc[h] = fmaf(e0[h], xv0, fmaf(e1[h], xv1, acc[h]));
        }
      }
      if (i < dg) {
        float xv0 = x[(size_t)srcs[beg + i] * 64 + lane];
#pragma unroll
        for (int j = 0; j < 5; j++) {
          float2 a = exv[(size_t)(beg + i) * 5 + j];
          den[2 * j] += a.x;
          den[2 * j + 1] += a.y;
          acc[2 * j] = fmaf(a.x, xv0, acc[2 * j]);
          acc[2 * j + 1] = fmaf(a.y, xv0, acc[2 * j + 1]);
        }
      }
    }
#pragma unroll
    for (int h = 0; h < 10; h++)
      zs[ni][68 * h + lane] = (dg > 0) ? acc[h] / den[h] : 0.f;
  }
  __syncthreads();
  // ---- phase 2: GEMM (W double-buffered) + relu + head-sum + el2/er2 ----
  const int f4 = f % 160;         // outputs 4*f4 .. 4*f4+3
  const int ng = f / 160;         // node group: nodes ng*4 .. ng*4+3
  const int head = f4 >> 4;
  const int base = 68 * head;
  float acc2[4][4];
#pragma unroll
  for (int i = 0; i < 4; i++)
#pragma unroll
    for (int j = 0; j < 4; j++) acc2[i][j] = 0.f;
  const float4* W4 = (const float4*)W;
  float4 wn[4];
#pragma unroll
  for (int j = 0; j < 4; j++) wn[j] = W4[(size_t)j * 160 + f4];
#pragma unroll
  for (int k4 = 0; k4 < 16; k4++) {
    float4 wc[4];
#pragma unroll
    for (int j = 0; j < 4; j++) wc[j] = wn[j];
    if (k4 < 15) {
#pragma unroll
      for (int j = 0; j < 4; j++) wn[j] = W4[(size_t)(4 * (k4 + 1) + j) * 160 + f4];
    }
    float4 zq[4];
#pragma unroll
    for (int i = 0; i < 4; i++)
      zq[i] = *(const float4*)&zs[ng * 4 + i][base + 4 * k4];
#pragma unroll
    for (int j4 = 0; j4 < 4; j4++) {
      const float4 w4 = wc[j4];
#pragma unroll
      for (int i = 0; i < 4; i++) {
        const float zv = j4 == 0 ? zq[i].x : j4 == 1 ? zq[i].y : j4 == 2 ? zq[i].z : zq[i].w;
        acc2[i][0] = fmaf(zv, w4.x, acc2[i][0]);
        acc2[i][1] = fmaf(zv, w4.y, acc2[i][1]);
        acc2[i][2] = fmaf(zv, w4.z, acc2[i][2]);
        acc2[i][3] = fmaf(zv, w4.w, acc2[i][3]);
      }
    }
  }
  const float4 b4 = ((const float4*)bb)[f4];
  __syncthreads();
#pragma unroll
  for (int i = 0; i < 4; i++) {
    float* row = &zs[ng * 4 + i][ZPAD(4 * f4)];   // 4 consecutive (same head)
    row[0] = fmaxf(acc2[i][0] + b4.x, 0.f);
    row[1] = fmaxf(acc2[i][1] + b4.y, 0.f);
    row[2] = fmaxf(acc2[i][2] + b4.z, 0.f);
    row[3] = fmaxf(acc2[i][3] + b4.w, 0.f);
  }
  __syncthreads();
  for (int idx = threadIdx.x; idx < NPB * 64; idx += 640) {
    const int i = idx >> 6, d = idx & 63;
    float s = 0.f;
#pragma unroll
    for (int h = 0; h < 10; h++) s += zs[i][68 * h + d];
    const int n = n0 + i;
    float pl = s * wal2[d], pr = s * war2[d];
#pragma unroll
    for (int off = 32; off >= 1; off >>= 1) {
      pl += __shfl_xor(pl, off);
      pr += __shfl_xor(pr, off);
    }
    if (n < N) {
      h1sum[(size_t)n * 64 + d] = s;
      if (lane == 0) { el2[n] = pl; er2[n] = pr; }
    }
  }
}

// ---------------------------------------------------------------------------
// FUSED layer 2: aggregation (precomputed ex2, one wave per node) -> LDS
// -> GEMM + relu + block-local segment-max readout. 256 threads, 16 nodes.
// ---------------------------------------------------------------------------
__global__ void aggr_gemm2_readout_kernel(
    const int* __restrict__ rpA, const int* __restrict__ degA, const int* __restrict__ srcsA,
    const float* __restrict__ hA, const float* __restrict__ exA,
    const float* __restrict__ WA, const float* __restrict__ bA,
    const int* __restrict__ gidA, int NA, int coA, int nbA,
    const int* __restrict__ rpB, const int* __restrict__ degB, const int* __restrict__ srcsB,
    const float* __restrict__ hB, const float* __restrict__ exB,
    const float* __restrict__ WB, const float* __restrict__ bB,
    const int* __restrict__ gidB, int NB, int coB,
    float* __restrict__ readout) {
  constexpr int NPB = 16;
  __shared__ float zs[NPB][64];
  __shared__ float vals[NPB][128];
  __shared__ int gids[NPB];
  const int *rp, *degp, *srcs; const float *hin, *ex, *W, *bb; const int* gid;
  int N, colOff, tile;
  if (blockIdx.x < (unsigned)nbA) {
    rp=rpA; degp=degA; srcs=srcsA; hin=hA; ex=exA; W=WA; bb=bA; gid=gidA;
    N=NA; colOff=coA; tile=blockIdx.x;
  } else {
    rp=rpB; degp=degB; srcs=srcsB; hin=hB; ex=exB; W=WB; bb=bB; gid=gidB;
    N=NB; colOff=coB; tile=blockIdx.x-nbA;
  }
  const int f = threadIdx.x;      // 256
  const int wv = f >> 6, lane = f & 63;
  const int n0 = tile * NPB;
  // ---- phase 1: aggregation into LDS ----
  for (int ni = wv; ni < NPB; ni += 4) {
    const int n = n0 + ni;
    float den = 0.f, acc = 0.f;
    int dg = 0;
    if (n < N) {
      const int beg = rp[n];
      dg = degp[n];
      int i = 0;
      for (; i + 1 < dg; i += 2) {
        int s0 = srcs[beg + i], s1 = srcs[beg + i + 1];
        float e0 = ex[beg + i], e1 = ex[beg + i + 1];
        den += e0 + e1;
        acc = fmaf(e0, hin[(size_t)s0 * 64 + lane], fmaf(e1, hin[(size_t)s1 * 64 + lane], acc));
      }
      if (i < dg) {
        float e0 = ex[beg + i];
        den += e0;
        acc = fmaf(e0, hin[(size_t)srcs[beg + i] * 64 + lane], acc);
      }
    }
    zs[ni][lane] = (dg > 0) ? acc / den : 0.f;
  }
  if (f < NPB) gids[f] = (n0 + f < N) ? gid[n0 + f] : -1;
  __syncthreads();
  // ---- phase 2: GEMM + relu ----
  const int col = f & 127, nb = f >> 7;   // 2 groups x 8 nodes
  float acc8[8];
#pragma unroll
  for (int i = 0; i < 8; i++) acc8[i] = 0.f;
#pragma unroll 4
  for (int k4 = 0; k4 < 16; k4++) {
    const float w0 = W[(size_t)(4 * k4 + 0) * 128 + col];
    const float w1 = W[(size_t)(4 * k4 + 1) * 128 + col];
    const float w2 = W[(size_t)(4 * k4 + 2) * 128 + col];
    const float w3 = W[(size_t)(4 * k4 + 3) * 128 + col];
#pragma unroll
    for (int i = 0; i < 8; i++) {
      float4 zq = *(const float4*)&zs[nb * 8 + i][4 * k4];
      acc8[i] = fmaf(zq.x, w0, fmaf(zq.y, w1, fmaf(zq.z, w2, fmaf(zq.w, w3, acc8[i]))));
    }
  }
  const float bbf = bb[col];
#pragma unroll
  for (int i = 0; i < 8; i++) vals[nb * 8 + i][col] = fmaxf(acc8[i] + bbf, 0.f);
  __syncthreads();
  // ---- phase 3: run-merge over sorted gids; one atomic per run per column ----
  if (f < 128) {
    float run = 0.f;
    int curg = -1;
#pragma unroll
    for (int i = 0; i < NPB; i++) {
      int g = gids[i];
      if (g < 0) break;
      if (g != curg) {
        if (curg >= 0)
          atomicMax((unsigned int*)&readout[curg * 256 + colOff + f], __float_as_uint(run));
        curg = g;
        run = 0.f;
      }
      run = fmaxf(run, vals[i][f]);
    }
    if (curg >= 0)
      atomicMax((unsigned int*)&readout[curg * 256 + colOff + f], __float_as_uint(run));
  }
}

// MLP: relu(concat @ W1 + b1) @ W2 + b2 -> relu -> out[32]
__global__ void mlp_kernel(const float* __restrict__ readout, const float* __restrict__ W1,
                           const float* __restrict__ b1, const float* __restrict__ W2,
                           const float* __restrict__ b2, float* __restrict__ out) {
  int b = blockIdx.x;   // 32
  int j = threadIdx.x;  // 128
  __shared__ float rs[256];
  rs[j] = readout[b * 256 + j];
  rs[j + 128] = readout[b * 256 + 128 + j];
  __syncthreads();
  float acc = b1[j];
#pragma unroll 8
  for (int k = 0; k < 256; k++) acc += rs[k] * W1[k * 128 + j];
  acc = fmaxf(acc, 0.f);
  float p = acc * W2[j];
#pragma unroll
  for (int off = 32; off >= 1; off >>= 1) p += __shfl_xor(p, off);
  __shared__ float wsum[2];
  if ((threadIdx.x & 63) == 0) wsum[threadIdx.x >> 6] = p;
  __syncthreads();
  if (threadIdx.x == 0) {
    float s = wsum[0] + wsum[1] + b2[0];
    out[b] = fmaxf(s, 0.f);
  }
}

// ---------------------------------------------------------------------------
extern "C" void kernel_launch(void* const* d_in, const int* in_sizes, int n_in,
                              void* d_out, int out_size, void* d_ws, size_t ws_size,
                              hipStream_t stream) {
  const float* x_lig = (const float*)d_in[0];
  const int* src_lig = (const int*)d_in[1];
  const int* dst_lig = (const int*)d_in[2];
  const int* gid_lig = (const int*)d_in[3];
  const float* x_rec = (const float*)d_in[4];
  const int* src_rec = (const int*)d_in[5];
  const int* dst_rec = (const int*)d_in[6];
  const int* gid_rec = (const int*)d_in[7];
  const float* W1l = (const float*)d_in[8];
  const float* al1l = (const float*)d_in[9];
  const float* ar1l = (const float*)d_in[10];
  const float* b1l = (const float*)d_in[11];
  const float* W2l = (const float*)d_in[12];
  const float* al2l = (const float*)d_in[13];
  const float* ar2l = (const float*)d_in[14];
  const float* b2l = (const float*)d_in[15];
  const float* W1r = (const float*)d_in[16];
  const float* al1r = (const float*)d_in[17];
  const float* ar1r = (const float*)d_in[18];
  const float* b1r = (const float*)d_in[19];
  const float* W2r = (const float*)d_in[20];
  const float* al2r = (const float*)d_in[21];
  const float* ar2r = (const float*)d_in[22];
  const float* b2r = (const float*)d_in[23];
  const float* W_lin1 = (const float*)d_in[24];
  const float* b_lin1 = (const float*)d_in[25];
  const float* W_lin2 = (const float*)d_in[26];
  const float* b_lin2 = (const float*)d_in[27];

  const int NL = 10000, EL = 80000, NR = 30000, ER = 480000;
  float* p = (float*)d_ws;
  float* ex1L = p;    p += (size_t)EL * 10;
  float* ex1R = p;    p += (size_t)ER * 10;
  float* ex2L = p;    p += EL;
  float* ex2R = p;    p += ER;
  float* h1L = p;     p += (size_t)NL * 64;
  float* h1R = p;     p += (size_t)NR * 64;
  float* el1L = p;    p += (size_t)NL * 10;
  float* er1L = p;    p += (size_t)NL * 10;
  float* el1R = p;    p += (size_t)NR * 10;
  float* er1R = p;    p += (size_t)NR * 10;
  float* el2L = p;    p += NL;
  float* er2L = p;    p += NL;
  float* el2R = p;    p += NR;
  float* er2R = p;    p += NR;
  float* wal1l = p;   p += 640;
  float* war1l = p;   p += 640;
  float* wal1r = p;   p += 640;
  float* war1r = p;   p += 640;
  float* wal2l = p;   p += 64;
  float* war2l = p;   p += 64;
  float* wal2r = p;   p += 64;
  float* war2r = p;   p += 64;
  float* zero_base = p;
  float* readout = p; p += 32 * 256;
  int* ip = (int*)p;
  int* degL = ip;     ip += NL;
  int* cntL = ip;     ip += 1;
  int* degR = ip;     ip += NR;
  int* cntR = ip;     ip += 1;
  size_t zero_bytes = (size_t)((char*)ip - (char*)zero_base);
  int* rpL = ip;      ip += NL;
  int* curL = ip;     ip += NL;
  int* srcsL = ip;    ip += EL;
  int* rpR = ip;      ip += NR;
  int* curR = ip;     ip += NR;
  int* srcsR = ip;    ip += ER;
  int* eslotL = ip;   ip += EL;
  int* eslotR = ip;   ip += ER;

  hipMemsetAsync(zero_base, 0, zero_bytes, stream);

  prep_wal2_kernel<10, 64><<<160, 512, 0, stream>>>(W1l, al1l, ar1l, wal1l, war1l, 80,
                                                    W1r, al1r, ar1r, wal1r, war1r);
  prep_wal2_kernel<1, 128><<<16, 512, 0, stream>>>(W2l, al2l, ar2l, wal2l, war2l, 8,
                                                   W2r, al2r, ar2r, wal2r, war2r);
  deg2_kernel<<<cdiv(EL, 256) + cdiv(ER, 256), 256, 0, stream>>>(
      dst_lig, degL, EL, cdiv(EL, 256), dst_rec, degR, ER);
  rowptr2_kernel<<<cdiv(NL, 256) + cdiv(NR, 256), 256, 0, stream>>>(
      degL, rpL, curL, cntL, NL, cdiv(NL, 256), degR, rpR, curR, cntR, NR);
  elr10_2_kernel<<<cdiv(NL, 4) + cdiv(NR, 4), 256, 0, stream>>>(
      x_lig, wal1l, war1l, el1L, er1L, NL, cdiv(NL, 4),
      x_rec, wal1r, war1r, el1R, er1R, NR);
  scatter_ex2_kernel<<<cdiv(EL, 256) + cdiv(ER, 256), 256, 0, stream>>>(
      src_lig, dst_lig, curL, srcsL, el1L, er1L, ex1L, eslotL, EL, cdiv(EL, 256),
      src_rec, dst_rec, curR, srcsR, el1R, er1R, ex1R, eslotR, ER);
  aggr_gemm1_kernel<<<cdiv(NL, 16) + cdiv(NR, 16), 640, 0, stream>>>(
      rpL, degL, srcsL, x_lig, ex1L, W1l, b1l, wal2l, war2l, h1L, el2L, er2L, NL, cdiv(NL, 16),
      rpR, degR, srcsR, x_rec, ex1R, W1r, b1r, wal2r, war2r, h1R, el2R, er2R, NR);
  ex2_2_kernel<<<cdiv(EL, 256) + cdiv(ER, 256), 256, 0, stream>>>(
      src_lig, dst_lig, eslotL, el2L, er2L, ex2L, EL, cdiv(EL, 256),
      src_rec, dst_rec, eslotR, el2R, er2R, ex2R, ER);
  aggr_gemm2_readout_kernel<<<cdiv(NL, 16) + cdiv(NR, 16), 256, 0, stream>>>(
      rpL, degL, srcsL, h1L, ex2L, W2l, b2l, gid_lig, NL, 0, cdiv(NL, 16),
      rpR, degR, srcsR, h1R, ex2R, W2r, b2r, gid_rec, NR, 128, readout);

  mlp_kernel<<<32, 128, 0, stream>>>(readout, W_lin1, b_lin1, W_lin2, b_lin2, (float*)d_out);
}